// Round 6
// baseline (2140.219 us; speedup 1.0000x reference)
//
#include <hip/hip_runtime.h>
#include <math.h>

#define Bq 16
#define Hc 384
#define Tt 2048
#define N2 32
#define LYR 6
#define HFq 1536
#define TWOH 768
#define CHUNK 64
#define NCH (Tt/CHUNK)   // 32
#define NJ (Bq*NCH)      // 512 chunk-columns per head
#define UH (NJ*CHUNK)    // 32768 elements per head in U/St/Y layouts

typedef __bf16 bf16x8 __attribute__((ext_vector_type(8)));
typedef float floatx4 __attribute__((ext_vector_type(4)));
typedef _Float16 f16_t;
typedef f16_t fp16x8 __attribute__((ext_vector_type(8)));
typedef f16_t fp16x4 __attribute__((ext_vector_type(4)));

__device__ __forceinline__ unsigned short bfbits(float f) {
  union { float f; unsigned u; } x; x.f = f;
  return (unsigned short)((x.u + 0x7FFF + ((x.u >> 16) & 1)) >> 16);
}

// async global->LDS, 16B per lane; dest is wave-uniform base, HW writes lane i
// at base + i*16B (linear). Source address is per-lane.
__device__ __forceinline__ void gl_lds16(const void* g, void* l) {
  __builtin_amdgcn_global_load_lds(
      (const __attribute__((address_space(1))) void*)g,
      (__attribute__((address_space(3))) void*)l, 16, 0, 0);
}

// ---------------- param precompute (fp64 for accuracy) ----------------
__global__ void param_kernel(const float* __restrict__ log_dt,
                             const float* __restrict__ A_re, const float* __restrict__ A_im,
                             const float* __restrict__ C_re, const float* __restrict__ C_im,
                             float* __restrict__ wre, float* __restrict__ wim,
                             float* __restrict__ cdre, float* __restrict__ cdim,
                             float* __restrict__ wSre, float* __restrict__ wSim) {
  int idx = blockIdx.x * blockDim.x + threadIdx.x;
  if (idx >= LYR * Hc * N2) return;
  int hn = idx / N2;
  double dt = exp((double)log_dt[hn]);
  double are = (double)A_re[idx], aim = (double)A_im[idx];
  double dre = are * dt, dimv = aim * dt;
  double er = exp(dre);
  double wr = er * cos(dimv), wi_ = er * sin(dimv);
  double den = are * are + aim * aim;
  double nr = wr - 1.0, ni = wi_;
  double qr = (nr * are + ni * aim) / den;
  double qi = (ni * are - nr * aim) / den;
  double cr = (double)C_re[idx], ci = (double)C_im[idx];
  cdre[idx] = (float)(2.0 * (cr * qr - ci * qi));
  cdim[idx] = (float)(2.0 * (cr * qi + ci * qr));
  wre[idx] = (float)wr; wim[idx] = (float)wi_;
  double es = exp(dre * (double)CHUNK);
  wSre[idx] = (float)(es * cos(dimv * (double)CHUNK));
  wSim[idx] = (float)(es * sin(dimv * (double)CHUNK));
}

// ---------------- weight fp32 -> bf16 (RNE) ----------------
__global__ void cvt_bf16_kernel(const float* __restrict__ in, unsigned short* __restrict__ out,
                                int n4) {
  int idx = blockIdx.x * 256 + threadIdx.x;
  if (idx >= n4) return;
  float4 v = ((const float4*)in)[idx];
  ushort4 o;
  o.x = bfbits(v.x); o.y = bfbits(v.y); o.z = bfbits(v.z); o.w = bfbits(v.w);
  ((ushort4*)out)[idx] = o;
}

// ---------------- transpose (B,C,T) -> (B,T,C) ----------------
__global__ __launch_bounds__(256) void transpose_fwd(const float* __restrict__ in,
                                                     float* __restrict__ out) {
  __shared__ float tile[32][33];
  int tx = threadIdx.x, ty = threadIdx.y;
  int t0 = blockIdx.x * 32, c0 = blockIdx.y * 32, b = blockIdx.z;
#pragma unroll
  for (int k = 0; k < 4; k++)
    tile[ty + 8 * k][tx] = in[((size_t)(b * Hc + c0 + ty + 8 * k)) * Tt + t0 + tx];
  __syncthreads();
#pragma unroll
  for (int k = 0; k < 4; k++)
    out[((size_t)(b * Tt + t0 + ty + 8 * k)) * Hc + c0 + tx] = tile[tx][ty + 8 * k];
}

// ---------------- transpose (B,T,C) -> (B,C,T) with mask ----------------
__global__ __launch_bounds__(256) void transpose_bwd(const float* __restrict__ in,
                                                     const float* __restrict__ mask,
                                                     float* __restrict__ out) {
  __shared__ float tile[32][33];
  int tx = threadIdx.x, ty = threadIdx.y;
  int t0 = blockIdx.x * 32, c0 = blockIdx.y * 32, b = blockIdx.z;
#pragma unroll
  for (int k = 0; k < 4; k++)
    tile[ty + 8 * k][tx] = in[((size_t)(b * Tt + t0 + ty + 8 * k)) * Hc + c0 + tx];
  __syncthreads();
  float mv = mask[(size_t)b * Tt + t0 + tx];
#pragma unroll
  for (int k = 0; k < 4; k++)
    out[((size_t)(b * Hc + c0 + ty + 8 * k)) * Tt + t0 + tx] = tile[tx][ty + 8 * k] * mv;
}

// ---------------- pack: xT (B,T,C) fp32 * mask -> U[h][j][tau] fp16 ----------------
__global__ __launch_bounds__(256) void pack_u(const float* __restrict__ xT,
                                              const float* __restrict__ mask,
                                              f16_t* __restrict__ U) {
  __shared__ float tile[64][65];
  int tid = threadIdx.x;
  int t0 = blockIdx.x * 64, h0 = blockIdx.y * 64, b = blockIdx.z;
#pragma unroll
  for (int p = 0; p < 4; p++) {
    int idx = p * 256 + tid;
    int row = idx >> 4, c4 = (idx & 15) * 4;
    float4 v = *(const float4*)&xT[((size_t)(b * Tt + t0 + row)) * Hc + h0 + c4];
    float mv = mask[(size_t)b * Tt + t0 + row];
    tile[row][c4] = v.x * mv; tile[row][c4 + 1] = v.y * mv;
    tile[row][c4 + 2] = v.z * mv; tile[row][c4 + 3] = v.w * mv;
  }
  __syncthreads();
#pragma unroll
  for (int p = 0; p < 2; p++) {
    int idx = p * 256 + tid;
    int hr = idx >> 3, g = (idx & 7) * 8;
    fp16x8 o;
#pragma unroll
    for (int i = 0; i < 8; i++) o[i] = (f16_t)tile[g + i][hr];
    *(fp16x8*)&U[(size_t)(h0 + hr) * UH + (size_t)b * Tt + t0 + g] = o;
  }
}

// ---------------- build per-head matrices: Ag = [T | V] (64x128), Wg (64x64) ----------------
__global__ __launch_bounds__(256) void build_mats(
    const float* __restrict__ wre, const float* __restrict__ wim,
    const float* __restrict__ cdre, const float* __restrict__ cdim,
    f16_t* __restrict__ Ag, f16_t* __restrict__ Wg) {
  __shared__ float pre[65][32], pim[65][32], Kc[64], cdr_s[32], cdi_s[32];
  int h = blockIdx.x, tid = threadIdx.x;
  if (tid < 32) {
    float wr = wre[h * N2 + tid], wi = wim[h * N2 + tid];
    cdr_s[tid] = cdre[h * N2 + tid];
    cdi_s[tid] = cdim[h * N2 + tid];
    float pr = 1.f, pi = 0.f;
    for (int p = 0; p <= 64; p++) {
      pre[p][tid] = pr; pim[p][tid] = pi;
      float nr2 = pr * wr - pi * wi;
      pi = pr * wi + pi * wr;
      pr = nr2;
    }
  }
  __syncthreads();
  if (tid < 64) {
    float s = 0.f;
    for (int n = 0; n < 32; n++)
      s = fmaf(cdr_s[n], pre[tid][n], fmaf(-cdi_s[n], pim[tid][n], s));
    Kc[tid] = s;
  }
  __syncthreads();
  for (int i = tid; i < 64 * 128; i += 256) {
    int m = i >> 7, k = i & 127;
    float v;
    if (k < 64) {
      v = (m >= k) ? Kc[m - k] : 0.f;
    } else {
      int kk = k - 64, n = kk >> 1;
      v = (kk & 1) ? -fmaf(cdr_s[n], pim[m + 1][n], cdi_s[n] * pre[m + 1][n])
                   :  fmaf(cdr_s[n], pre[m + 1][n], -cdi_s[n] * pim[m + 1][n]);
    }
    Ag[(size_t)h * 8192 + i] = (f16_t)v;
  }
  for (int i = tid; i < 64 * 64; i += 256) {
    int m = i >> 6, tau = i & 63, n = m >> 1;
    float v = (m & 1) ? pim[63 - tau][n] : pre[63 - tau][n];
    Wg[(size_t)h * 4096 + i] = (f16_t)v;
  }
}

// ---------------- state GEMM: S_end[m'][j] = Wg . U  (per head), fp16 out ----------------
__global__ __launch_bounds__(256) void gemm_state(const f16_t* __restrict__ U,
                                                  const f16_t* __restrict__ Wg,
                                                  f16_t* __restrict__ St) {
  __shared__ f16_t Aw[64][72];
  __shared__ f16_t Bu[128][72];
  int tid = threadIdx.x;
  int j0 = blockIdx.x * 128, h = blockIdx.y;
#pragma unroll
  for (int p = 0; p < 2; p++) {
    int idx = p * 256 + tid;
    int row = idx >> 3, c8 = (idx & 7) * 8;
    *(fp16x8*)&Aw[row][c8] = *(const fp16x8*)&Wg[(size_t)h * 4096 + row * 64 + c8];
  }
#pragma unroll
  for (int p = 0; p < 4; p++) {
    int idx = p * 256 + tid;
    int row = idx >> 3, c8 = (idx & 7) * 8;
    *(fp16x8*)&Bu[row][c8] =
        *(const fp16x8*)&U[(size_t)h * UH + (size_t)(j0 + row) * CHUNK + c8];
  }
  __syncthreads();
  int wave = tid >> 6, lane = tid & 63, l16 = lane & 15, quad = lane >> 4;
  int m0 = wave * 16;
  floatx4 acc[8];
#pragma unroll
  for (int jt = 0; jt < 8; jt++) acc[jt] = (floatx4){0.f, 0.f, 0.f, 0.f};
#pragma unroll
  for (int kk = 0; kk < 2; kk++) {
    fp16x8 a = *(const fp16x8*)&Aw[m0 + l16][kk * 32 + quad * 8];
#pragma unroll
    for (int jt = 0; jt < 8; jt++) {
      fp16x8 bb = *(const fp16x8*)&Bu[jt * 16 + l16][kk * 32 + quad * 8];
      acc[jt] = __builtin_amdgcn_mfma_f32_16x16x32_f16(a, bb, acc[jt], 0, 0, 0);
    }
  }
#pragma unroll
  for (int jt = 0; jt < 8; jt++) {
    int j = j0 + jt * 16 + l16;
    fp16x4 o;
#pragma unroll
    for (int r = 0; r < 4; r++) o[r] = (f16_t)acc[jt][r];
    *(fp16x4*)&St[(size_t)h * UH + (size_t)j * CHUNK + m0 + quad * 4] = o;
  }
}

// ---------------- prefix over chunks: local end-states -> carry-in states ----------------
__global__ __launch_bounds__(256) void scan_prefix2(
    f16_t* __restrict__ St,
    const float* __restrict__ wSre, const float* __restrict__ wSim) {
  int gid = blockIdx.x * 256 + threadIdx.x;  // (h*16 + b)*32 + n
  if (gid >= Hc * Bq * N2) return;
  int n = gid & 31;
  int b = (gid >> 5) & 15;
  int h = gid >> 9;
  float wr = wSre[h * N2 + n], wi = wSim[h * N2 + n];
  float cr = 0.f, ci = 0.f;
  unsigned* base = (unsigned*)(St + (size_t)h * UH + (size_t)b * Tt + 2 * n);
  for (int c = 0; c < NCH; c++) {
    union { unsigned u; f16_t h2[2]; } in, out;
    in.u = base[c * 32];
    float sre = (float)in.h2[0], sim = (float)in.h2[1];
    out.h2[0] = (f16_t)cr; out.h2[1] = (f16_t)ci;
    base[c * 32] = out.u;
    float c0 = cr;
    cr = fmaf(wr, c0, fmaf(-wi, ci, sre));
    ci = fmaf(wr, ci, fmaf(wi, c0, sim));
  }
}

// ---------------- out GEMM: Y = gelu([T|V].[U;S0] + D*u), bf16 out [h][j][tau] ----------------
__global__ __launch_bounds__(256) void gemm_out(
    const f16_t* __restrict__ U, const f16_t* __restrict__ Ag,
    const f16_t* __restrict__ St, const float* __restrict__ Dv,
    unsigned short* __restrict__ Yb) {
  __shared__ f16_t Aa[64][136];
  __shared__ f16_t Bb[128][136];
  int tid = threadIdx.x;
  int j0 = blockIdx.x * 128, h = blockIdx.y;
#pragma unroll
  for (int p = 0; p < 4; p++) {
    int idx = p * 256 + tid;
    int row = idx >> 4, c8 = (idx & 15) * 8;
    *(fp16x8*)&Aa[row][c8] = *(const fp16x8*)&Ag[(size_t)h * 8192 + row * 128 + c8];
  }
#pragma unroll
  for (int p = 0; p < 4; p++) {
    int idx = p * 256 + tid;
    int row = idx >> 3, c8 = (idx & 7) * 8;
    *(fp16x8*)&Bb[row][c8] =
        *(const fp16x8*)&U[(size_t)h * UH + (size_t)(j0 + row) * CHUNK + c8];
    *(fp16x8*)&Bb[row][64 + c8] =
        *(const fp16x8*)&St[(size_t)h * UH + (size_t)(j0 + row) * CHUNK + c8];
  }
  __syncthreads();
  int wave = tid >> 6, lane = tid & 63, l16 = lane & 15, quad = lane >> 4;
  int m0 = wave * 16;
  floatx4 acc[8];
#pragma unroll
  for (int jt = 0; jt < 8; jt++) acc[jt] = (floatx4){0.f, 0.f, 0.f, 0.f};
#pragma unroll
  for (int kk = 0; kk < 4; kk++) {
    fp16x8 a = *(const fp16x8*)&Aa[m0 + l16][kk * 32 + quad * 8];
#pragma unroll
    for (int jt = 0; jt < 8; jt++) {
      fp16x8 bb = *(const fp16x8*)&Bb[jt * 16 + l16][kk * 32 + quad * 8];
      acc[jt] = __builtin_amdgcn_mfma_f32_16x16x32_f16(a, bb, acc[jt], 0, 0, 0);
    }
  }
  float d = Dv[h];
  int tb = m0 + quad * 4;
#pragma unroll
  for (int jt = 0; jt < 8; jt++) {
    int jr = jt * 16 + l16;
    fp16x4 u4 = *(const fp16x4*)&Bb[jr][tb];
    ushort4 o;
#pragma unroll
    for (int r = 0; r < 4; r++) {
      float v = fmaf(d, (float)u4[r], acc[jt][r]);
      v = 0.5f * v * (1.0f + erff(v * 0.70710678118654752f));
      ((unsigned short*)&o)[r] = bfbits(v);
    }
    *(ushort4*)&Yb[(size_t)h * UH + (size_t)(j0 + jr) * CHUNK + tb] = o;
  }
}

// ---------------- unpack: Yb[h][j][tau] bf16 -> ybf (B,T,C) bf16 ----------------
__global__ __launch_bounds__(256) void unpack_y(const unsigned short* __restrict__ Yb,
                                                unsigned short* __restrict__ yb) {
  __shared__ unsigned short tile[64][65];
  int tid = threadIdx.x;
  int t0 = blockIdx.x * 64, h0 = blockIdx.y * 64, b = blockIdx.z;
#pragma unroll
  for (int p = 0; p < 2; p++) {
    int idx = p * 256 + tid;
    int hr = idx >> 3, g = (idx & 7) * 8;
    uint4 v = *(const uint4*)&Yb[(size_t)(h0 + hr) * UH + (size_t)b * Tt + t0 + g];
    const unsigned short* s = (const unsigned short*)&v;
#pragma unroll
    for (int i = 0; i < 8; i++) tile[hr][g + i] = s[i];
  }
  __syncthreads();
#pragma unroll
  for (int p = 0; p < 2; p++) {
    int idx = p * 256 + tid;
    int tr = idx >> 3, g = (idx & 7) * 8;
    unsigned short o[8];
#pragma unroll
    for (int i = 0; i < 8; i++) o[i] = tile[g + i][tr];
    *(uint4*)&yb[((size_t)(b * Tt + t0 + tr)) * Hc + h0 + g] = *(uint4*)o;
  }
}

// ---------------- MFMA GEMM: out(B,T,N) = act(B,T,K) x W(N,K)^T ----------------
// Staging via global_load_lds width=16 (no VGPR roundtrip, no staging VALU):
// wave w, round r stages rows [(w+4r)*16, +16) of the [128][32] bf16 tile;
// lane l sources row +(l>>2), col (l&3)*8 -> HW writes linearly at base+l*16B.
// EPI 0: outf = acc + bias                (fp32)
// EPI 1: outb = relu(acc + bias) * mask   (bf16)
// EPI 2: GLU: W has 2N rows; outf = (a+ba)*sigmoid(g+bg)  (fp32)
template <int EPI>
__global__ __launch_bounds__(256) void mfma_gemm(
    const __bf16* __restrict__ act, const __bf16* __restrict__ W,
    const float* __restrict__ bias, const float* __restrict__ mask,
    float* __restrict__ outf, unsigned short* __restrict__ outb,
    int K, int NOUT) {
  __shared__ __bf16 As[128][32];
  __shared__ __bf16 Bs[128][32];
  __shared__ __bf16 Bs2[(EPI == 2) ? 128 : 1][32];
  int tid = threadIdx.x;
  int b = blockIdx.z;
  int t0 = blockIdx.x * 128, n0 = blockIdx.y * 128;
  int wave = tid >> 6, lane = tid & 63, l16 = lane & 15, quad = lane >> 4;
  int wm = wave >> 1, wn = wave & 1;

  floatx4 acc[4][4];
  floatx4 accg[(EPI == 2) ? 4 : 1][4];
#pragma unroll
  for (int i = 0; i < 4; i++)
#pragma unroll
    for (int j = 0; j < 4; j++) {
      acc[i][j] = (floatx4){0.f, 0.f, 0.f, 0.f};
      if constexpr (EPI == 2) accg[i][j] = (floatx4){0.f, 0.f, 0.f, 0.f};
    }

  int srow = wave * 16 + (lane >> 2);     // + r*64 per round
  int scol = (lane & 3) * 8;
  const __bf16* aSrc = act + ((size_t)(b * Tt + t0 + srow)) * K + scol;
  const __bf16* bSrc = W + (size_t)(n0 + srow) * K + scol;
  const __bf16* gSrc = W + (size_t)(NOUT + n0 + srow) * K + scol;  // EPI2 only

  for (int k0 = 0; k0 < K; k0 += 32) {
#pragma unroll
    for (int r = 0; r < 2; r++) {
      gl_lds16(aSrc + k0 + (size_t)(64 * r) * K, &As[wave * 16 + r * 64][0]);
      gl_lds16(bSrc + k0 + (size_t)(64 * r) * K, &Bs[wave * 16 + r * 64][0]);
      if constexpr (EPI == 2)
        gl_lds16(gSrc + k0 + (size_t)(64 * r) * K, &Bs2[wave * 16 + r * 64][0]);
    }
    __syncthreads();   // drains vmcnt (global_load_lds) before any wave reads
    bf16x8 af[4], bfr[4], gfr[(EPI == 2) ? 4 : 1];
#pragma unroll
    for (int i = 0; i < 4; i++)
      af[i] = *(const bf16x8*)&As[wm * 64 + i * 16 + l16][quad * 8];
#pragma unroll
    for (int j = 0; j < 4; j++) {
      bfr[j] = *(const bf16x8*)&Bs[wn * 64 + j * 16 + l16][quad * 8];
      if constexpr (EPI == 2)
        gfr[j] = *(const bf16x8*)&Bs2[wn * 64 + j * 16 + l16][quad * 8];
    }
#pragma unroll
    for (int i = 0; i < 4; i++)
#pragma unroll
      for (int j = 0; j < 4; j++) {
        acc[i][j] = __builtin_amdgcn_mfma_f32_16x16x32_bf16(af[i], bfr[j], acc[i][j], 0, 0, 0);
        if constexpr (EPI == 2)
          accg[i][j] = __builtin_amdgcn_mfma_f32_16x16x32_bf16(af[i], gfr[j], accg[i][j], 0, 0, 0);
      }
    __syncthreads();   // WAR: all reads done before next stage overwrites
  }

  // epilogue: D row = t (i*16 + quad*4 + r), col = n (j*16 + l16)
#pragma unroll
  for (int i = 0; i < 4; i++) {
    int tb = t0 + wm * 64 + i * 16 + quad * 4;
    float mv[4];
    if constexpr (EPI == 1) {
#pragma unroll
      for (int r = 0; r < 4; r++) mv[r] = mask[(size_t)b * Tt + tb + r];
    }
#pragma unroll
    for (int j = 0; j < 4; j++) {
      int n = n0 + wn * 64 + j * 16 + l16;
      float bn = bias[n];
      float bg = (EPI == 2) ? bias[NOUT + n] : 0.f;
#pragma unroll
      for (int r = 0; r < 4; r++) {
        size_t o = ((size_t)(b * Tt + tb + r)) * NOUT + n;
        if constexpr (EPI == 0) {
          outf[o] = acc[i][j][r] + bn;
        } else if constexpr (EPI == 1) {
          float v = fmaxf(acc[i][j][r] + bn, 0.f) * mv[r];
          outb[o] = bfbits(v);
        } else {
          float a = acc[i][j][r] + bn;
          float g = accg[i][j][r] + bg;
          outf[o] = a / (1.f + expf(-g));
        }
      }
    }
  }
}

// ---------------- LayerNorm over C (contiguous), wave per row ----------------
__global__ __launch_bounds__(256) void ln_t(
    const float* __restrict__ in1, const float* __restrict__ in2,
    const float* __restrict__ mask, const float* __restrict__ gamma,
    const float* __restrict__ beta, float* __restrict__ out,
    unsigned short* __restrict__ outb, int m1, int m2) {
  int row = blockIdx.x * 4 + (threadIdx.x >> 6);  // b*Tt + t
  int lane = threadIdx.x & 63;
  float mv = mask[row];
  float f1 = m1 ? mv : 1.f;
  float f2 = m2 ? mv : 1.f;
  size_t base = (size_t)row * Hc;
  float v[6], sum = 0.f, sq = 0.f;
#pragma unroll
  for (int j = 0; j < 6; j++) {
    int idx = lane + 64 * j;
    float a = in1[base + idx] * f1 + in2[base + idx] * f2;
    v[j] = a; sum += a; sq = fmaf(a, a, sq);
  }
#pragma unroll
  for (int off = 32; off >= 1; off >>= 1) {
    sum += __shfl_xor(sum, off, 64);
    sq  += __shfl_xor(sq,  off, 64);
  }
  float m = sum * (1.f / Hc);
  float var = sq * (1.f / Hc) - m * m;
  float rs = rsqrtf(var + 1e-4f);
#pragma unroll
  for (int j = 0; j < 6; j++) {
    int idx = lane + 64 * j;
    float o = (v[j] - m) * rs * gamma[idx] + beta[idx];
    out[base + idx] = o;
    if (outb) outb[base + idx] = bfbits(o * mv);
  }
}

// ---------------- diagnostic ----------------
__global__ void diag_kernel(float* out, float v) {
  if (blockIdx.x == 0 && threadIdx.x == 0) out[0] = v;
}

extern "C" void kernel_launch(void* const* d_in, const int* in_sizes, int n_in,
                              void* d_out, int out_size, void* d_ws, size_t ws_size,
                              hipStream_t stream) {
  const float* x_in  = (const float*)d_in[0];
  const float* xmask = (const float*)d_in[1];
  const float* log_dt = (const float*)d_in[2];
  const float* A_re = (const float*)d_in[3];
  const float* A_im = (const float*)d_in[4];
  const float* C_re = (const float*)d_in[5];
  const float* C_im = (const float*)d_in[6];
  const float* Dv   = (const float*)d_in[7];
  const float* Wout = (const float*)d_in[8];
  const float* bout = (const float*)d_in[9];
  const float* g1   = (const float*)d_in[10];
  const float* be1  = (const float*)d_in[11];
  const float* W1   = (const float*)d_in[12];
  const float* bf1  = (const float*)d_in[13];
  const float* W2   = (const float*)d_in[14];
  const float* bf2  = (const float*)d_in[15];
  const float* g2   = (const float*)d_in[16];
  const float* be2  = (const float*)d_in[17];

  const size_t NXf   = (size_t)Bq * Hc * Tt;          // 12,582,912 floats
  const size_t NP    = (size_t)LYR * Hc * N2;         // 73,728
  const size_t YBFf  = NXf / 2;                       // bf16 y / x1b region, in floats
  const size_t HBFf  = (size_t)Bq * Tt * HFq / 2;     // bf16 h region, in floats
  const size_t WOUTf = (size_t)LYR * TWOH * Hc / 2;
  const size_t W1f   = (size_t)LYR * HFq * Hc / 2;
  const size_t W2f   = (size_t)LYR * Hc * HFq / 2;

  size_t need = 2 * NXf + YBFf + HBFf + WOUTf + W1f + W2f + 6 * NP;
  if (ws_size / 4 < need) {
    diag_kernel<<<1, 64, 0, stream>>>((float*)d_out, 1000.0f + (float)(ws_size >> 20));
    return;
  }

  float* ws = (float*)d_ws;
  float* xT   = ws;                       // (B,T,C) fp32 layer state
  float* tmp  = xT + NXf;                 // (B,T,C) fp32: U fp16 overlay, glu out, ffn2 out
  float* ybfF = tmp + NXf;                // bf16 (B,T,C): y, then x1*mask
  float* hbfF = ybfF + YBFf;              // bf16 (B,T,HF): ffn hidden; scan overlays
  float* wobF = hbfF + HBFf;              // bf16 weights
  float* w1bF = wobF + WOUTf;
  float* w2bF = w1bF + W1f;
  float* wre  = w2bF + W2f;
  float* wim  = wre + NP;
  float* cdre = wim + NP;
  float* cdim = cdre + NP;
  float* wSre = cdim + NP;
  float* wSim = wSre + NP;

  unsigned short* ybf = (unsigned short*)ybfF;
  unsigned short* hbf = (unsigned short*)hbfF;
  unsigned short* wob = (unsigned short*)wobF;
  unsigned short* w1b = (unsigned short*)w1bF;
  unsigned short* w2b = (unsigned short*)w2bF;
  float* x1 = (float*)d_out;              // (B,T,C) fp32 post-LN1 lives in d_out

  // scan overlays: U in tmp (first half); St/Yb/mats in hbf region (dead until FFN)
  f16_t* Ub   = (f16_t*)tmp;                                  // 12.58M fp16 = 6.29M fl
  f16_t* St16 = (f16_t*)hbfF;                                 // 12.58M fp16
  unsigned short* Ybi = (unsigned short*)(hbfF + YBFf);       // 12.58M bf16
  f16_t* Ag   = (f16_t*)(hbfF + 2 * YBFf);                    // 384*8192 fp16
  f16_t* Wg   = Ag + (size_t)384 * 8192;                      // 384*4096 fp16

  param_kernel<<<(LYR * Hc * N2 + 255) / 256, 256, 0, stream>>>(
      log_dt, A_re, A_im, C_re, C_im, wre, wim, cdre, cdim, wSre, wSim);
  cvt_bf16_kernel<<<(int)(2 * WOUTf + 1023) / 1024, 256, 0, stream>>>(Wout, wob, (int)(WOUTf / 2));
  cvt_bf16_kernel<<<(int)(2 * W1f + 1023) / 1024, 256, 0, stream>>>(W1, w1b, (int)(W1f / 2));
  cvt_bf16_kernel<<<(int)(2 * W2f + 1023) / 1024, 256, 0, stream>>>(W2, w2b, (int)(W2f / 2));
  transpose_fwd<<<dim3(Tt / 32, Hc / 32, Bq), dim3(32, 8), 0, stream>>>(x_in, xT);

  for (int i = 0; i < LYR; i++) {
    size_t po = (size_t)i * Hc * N2;

    // --- S4D scan via MFMA (chunked Toeplitz + carry) ---
    pack_u<<<dim3(Tt / 64, Hc / 64, Bq), 256, 0, stream>>>(xT, xmask, Ub);
    build_mats<<<Hc, 256, 0, stream>>>(wre + po, wim + po, cdre + po, cdim + po, Ag, Wg);
    gemm_state<<<dim3(NJ / 128, Hc), 256, 0, stream>>>(Ub, Wg, St16);
    scan_prefix2<<<(Hc * Bq * N2) / 256, 256, 0, stream>>>(St16, wSre + po, wSim + po);
    gemm_out<<<dim3(NJ / 128, Hc), 256, 0, stream>>>(Ub, Ag, St16, Dv + (size_t)i * Hc, Ybi);
    unpack_y<<<dim3(Tt / 64, Hc / 64, Bq), 256, 0, stream>>>(Ybi, ybf);

    // glu = GLU(Wout*y + bout) -> tmp (fp32)
    mfma_gemm<2><<<dim3(Tt / 128, Hc / 128, Bq), 256, 0, stream>>>(
        (const __bf16*)ybf, (const __bf16*)(wob + (size_t)i * TWOH * Hc),
        bout + (size_t)i * TWOH, xmask, tmp, nullptr, Hc, Hc);

    // x1 = LN(x*mask + glu) -> d_out fp32 ; x1b = bf16(x1*mask) -> ybf
    ln_t<<<(Bq * Tt) / 4, 256, 0, stream>>>(
        xT, tmp, xmask, g1 + (size_t)i * Hc, be1 + (size_t)i * Hc, x1, ybf, 1, 0);

    // h = bf16(relu(W1*x1b + bf1) * mask) -> hbf
    mfma_gemm<1><<<dim3(Tt / 128, HFq / 128, Bq), 256, 0, stream>>>(
        (const __bf16*)ybf, (const __bf16*)(w1b + (size_t)i * HFq * Hc),
        bf1 + (size_t)i * HFq, xmask, nullptr, hbf, Hc, HFq);

    // f = W2*h + bf2 -> tmp (fp32)
    mfma_gemm<0><<<dim3(Tt / 128, Hc / 128, Bq), 256, 0, stream>>>(
        (const __bf16*)hbf, (const __bf16*)(w2b + (size_t)i * Hc * HFq),
        bf2 + (size_t)i * Hc, xmask, tmp, nullptr, HFq, Hc);

    // x = LN(x1 + f*mask) -> xT
    ln_t<<<(Bq * Tt) / 4, 256, 0, stream>>>(
        x1, tmp, xmask, g2 + (size_t)i * Hc, be2 + (size_t)i * Hc, xT, nullptr, 0, 1);
  }

  transpose_bwd<<<dim3(Tt / 32, Hc / 32, Bq), dim3(32, 8), 0, stream>>>(xT, xmask, (float*)d_out);
}

// Round 7
// 1987.627 us; speedup vs baseline: 1.0768x; 1.0768x over previous
//
#include <hip/hip_runtime.h>
#include <math.h>

#define Bq 16
#define Hc 384
#define Tt 2048
#define N2 32
#define LYR 6
#define HFq 1536
#define TWOH 768
#define CHUNK 64
#define NCH (Tt/CHUNK)   // 32
#define NJ (Bq*NCH)      // 512 chunk-columns per head
#define UH (NJ*CHUNK)    // 32768 elements per head in U/St/Y layouts

typedef __bf16 bf16x8 __attribute__((ext_vector_type(8)));
typedef float floatx4 __attribute__((ext_vector_type(4)));
typedef _Float16 f16_t;
typedef f16_t fp16x8 __attribute__((ext_vector_type(8)));
typedef f16_t fp16x4 __attribute__((ext_vector_type(4)));

__device__ __forceinline__ unsigned short bfbits(float f) {
  union { float f; unsigned u; } x; x.f = f;
  return (unsigned short)((x.u + 0x7FFF + ((x.u >> 16) & 1)) >> 16);
}
__device__ __forceinline__ float bf2f(unsigned short u) {
  union { unsigned u; float f; } x; x.u = ((unsigned)u) << 16; return x.f;
}

// ---------------- param precompute (fp64 for accuracy) ----------------
__global__ void param_kernel(const float* __restrict__ log_dt,
                             const float* __restrict__ A_re, const float* __restrict__ A_im,
                             const float* __restrict__ C_re, const float* __restrict__ C_im,
                             float* __restrict__ wre, float* __restrict__ wim,
                             float* __restrict__ cdre, float* __restrict__ cdim,
                             float* __restrict__ wSre, float* __restrict__ wSim) {
  int idx = blockIdx.x * blockDim.x + threadIdx.x;
  if (idx >= LYR * Hc * N2) return;
  int hn = idx / N2;
  double dt = exp((double)log_dt[hn]);
  double are = (double)A_re[idx], aim = (double)A_im[idx];
  double dre = are * dt, dimv = aim * dt;
  double er = exp(dre);
  double wr = er * cos(dimv), wi_ = er * sin(dimv);
  double den = are * are + aim * aim;
  double nr = wr - 1.0, ni = wi_;
  double qr = (nr * are + ni * aim) / den;
  double qi = (ni * are - nr * aim) / den;
  double cr = (double)C_re[idx], ci = (double)C_im[idx];
  cdre[idx] = (float)(2.0 * (cr * qr - ci * qi));
  cdim[idx] = (float)(2.0 * (cr * qi + ci * qr));
  wre[idx] = (float)wr; wim[idx] = (float)wi_;
  double es = exp(dre * (double)CHUNK);
  wSre[idx] = (float)(es * cos(dimv * (double)CHUNK));
  wSim[idx] = (float)(es * sin(dimv * (double)CHUNK));
}

// ---------------- weight fp32 -> bf16 (RNE) ----------------
__global__ void cvt_bf16_kernel(const float* __restrict__ in, unsigned short* __restrict__ out,
                                int n4) {
  int idx = blockIdx.x * 256 + threadIdx.x;
  if (idx >= n4) return;
  float4 v = ((const float4*)in)[idx];
  ushort4 o;
  o.x = bfbits(v.x); o.y = bfbits(v.y); o.z = bfbits(v.z); o.w = bfbits(v.w);
  ((ushort4*)out)[idx] = o;
}

// ---------------- transpose (B,C,T) -> (B,T,C) ----------------
__global__ __launch_bounds__(256) void transpose_fwd(const float* __restrict__ in,
                                                     float* __restrict__ out) {
  __shared__ float tile[32][33];
  int tx = threadIdx.x, ty = threadIdx.y;
  int t0 = blockIdx.x * 32, c0 = blockIdx.y * 32, b = blockIdx.z;
#pragma unroll
  for (int k = 0; k < 4; k++)
    tile[ty + 8 * k][tx] = in[((size_t)(b * Hc + c0 + ty + 8 * k)) * Tt + t0 + tx];
  __syncthreads();
#pragma unroll
  for (int k = 0; k < 4; k++)
    out[((size_t)(b * Tt + t0 + ty + 8 * k)) * Hc + c0 + tx] = tile[tx][ty + 8 * k];
}

// ---------------- transpose (B,T,C) -> (B,C,T) with mask ----------------
__global__ __launch_bounds__(256) void transpose_bwd(const float* __restrict__ in,
                                                     const float* __restrict__ mask,
                                                     float* __restrict__ out) {
  __shared__ float tile[32][33];
  int tx = threadIdx.x, ty = threadIdx.y;
  int t0 = blockIdx.x * 32, c0 = blockIdx.y * 32, b = blockIdx.z;
#pragma unroll
  for (int k = 0; k < 4; k++)
    tile[ty + 8 * k][tx] = in[((size_t)(b * Tt + t0 + ty + 8 * k)) * Hc + c0 + tx];
  __syncthreads();
  float mv = mask[(size_t)b * Tt + t0 + tx];
#pragma unroll
  for (int k = 0; k < 4; k++)
    out[((size_t)(b * Hc + c0 + ty + 8 * k)) * Tt + t0 + tx] = tile[tx][ty + 8 * k] * mv;
}

// ---------------- pack: xT (B,T,C) fp32 * mask -> U[h][j][tau] fp16 ----------------
__global__ __launch_bounds__(256) void pack_u(const float* __restrict__ xT,
                                              const float* __restrict__ mask,
                                              f16_t* __restrict__ U) {
  __shared__ float tile[64][65];
  int tid = threadIdx.x;
  int t0 = blockIdx.x * 64, h0 = blockIdx.y * 64, b = blockIdx.z;
#pragma unroll
  for (int p = 0; p < 4; p++) {
    int idx = p * 256 + tid;
    int row = idx >> 4, c4 = (idx & 15) * 4;
    float4 v = *(const float4*)&xT[((size_t)(b * Tt + t0 + row)) * Hc + h0 + c4];
    float mv = mask[(size_t)b * Tt + t0 + row];
    tile[row][c4] = v.x * mv; tile[row][c4 + 1] = v.y * mv;
    tile[row][c4 + 2] = v.z * mv; tile[row][c4 + 3] = v.w * mv;
  }
  __syncthreads();
#pragma unroll
  for (int p = 0; p < 2; p++) {
    int idx = p * 256 + tid;
    int hr = idx >> 3, g = (idx & 7) * 8;
    fp16x8 o;
#pragma unroll
    for (int i = 0; i < 8; i++) o[i] = (f16_t)tile[g + i][hr];
    *(fp16x8*)&U[(size_t)(h0 + hr) * UH + (size_t)b * Tt + t0 + g] = o;
  }
}

// ---------------- build per-head matrices: Ag = [T | V] (64x128), Wg (64x64) ----------------
__global__ __launch_bounds__(256) void build_mats(
    const float* __restrict__ wre, const float* __restrict__ wim,
    const float* __restrict__ cdre, const float* __restrict__ cdim,
    f16_t* __restrict__ Ag, f16_t* __restrict__ Wg) {
  __shared__ float pre[65][32], pim[65][32], Kc[64], cdr_s[32], cdi_s[32];
  int h = blockIdx.x, tid = threadIdx.x;
  if (tid < 32) {
    float wr = wre[h * N2 + tid], wi = wim[h * N2 + tid];
    cdr_s[tid] = cdre[h * N2 + tid];
    cdi_s[tid] = cdim[h * N2 + tid];
    float pr = 1.f, pi = 0.f;
    for (int p = 0; p <= 64; p++) {
      pre[p][tid] = pr; pim[p][tid] = pi;
      float nr2 = pr * wr - pi * wi;
      pi = pr * wi + pi * wr;
      pr = nr2;
    }
  }
  __syncthreads();
  if (tid < 64) {
    float s = 0.f;
    for (int n = 0; n < 32; n++)
      s = fmaf(cdr_s[n], pre[tid][n], fmaf(-cdi_s[n], pim[tid][n], s));
    Kc[tid] = s;
  }
  __syncthreads();
  for (int i = tid; i < 64 * 128; i += 256) {
    int m = i >> 7, k = i & 127;
    float v;
    if (k < 64) {
      v = (m >= k) ? Kc[m - k] : 0.f;
    } else {
      int kk = k - 64, n = kk >> 1;
      v = (kk & 1) ? -fmaf(cdr_s[n], pim[m + 1][n], cdi_s[n] * pre[m + 1][n])
                   :  fmaf(cdr_s[n], pre[m + 1][n], -cdi_s[n] * pim[m + 1][n]);
    }
    Ag[(size_t)h * 8192 + i] = (f16_t)v;
  }
  for (int i = tid; i < 64 * 64; i += 256) {
    int m = i >> 6, tau = i & 63, n = m >> 1;
    float v = (m & 1) ? pim[63 - tau][n] : pre[63 - tau][n];
    Wg[(size_t)h * 4096 + i] = (f16_t)v;
  }
}

// ---------------- state GEMM: S_end[m'][j] = Wg . U  (per head), fp16 out ----------------
__global__ __launch_bounds__(256) void gemm_state(const f16_t* __restrict__ U,
                                                  const f16_t* __restrict__ Wg,
                                                  f16_t* __restrict__ St) {
  __shared__ f16_t Aw[64][72];
  __shared__ f16_t Bu[128][72];
  int tid = threadIdx.x;
  int j0 = blockIdx.x * 128, h = blockIdx.y;
#pragma unroll
  for (int p = 0; p < 2; p++) {
    int idx = p * 256 + tid;
    int row = idx >> 3, c8 = (idx & 7) * 8;
    *(fp16x8*)&Aw[row][c8] = *(const fp16x8*)&Wg[(size_t)h * 4096 + row * 64 + c8];
  }
#pragma unroll
  for (int p = 0; p < 4; p++) {
    int idx = p * 256 + tid;
    int row = idx >> 3, c8 = (idx & 7) * 8;
    *(fp16x8*)&Bu[row][c8] =
        *(const fp16x8*)&U[(size_t)h * UH + (size_t)(j0 + row) * CHUNK + c8];
  }
  __syncthreads();
  int wave = tid >> 6, lane = tid & 63, l16 = lane & 15, quad = lane >> 4;
  int m0 = wave * 16;
  floatx4 acc[8];
#pragma unroll
  for (int jt = 0; jt < 8; jt++) acc[jt] = (floatx4){0.f, 0.f, 0.f, 0.f};
#pragma unroll
  for (int kk = 0; kk < 2; kk++) {
    fp16x8 a = *(const fp16x8*)&Aw[m0 + l16][kk * 32 + quad * 8];
#pragma unroll
    for (int jt = 0; jt < 8; jt++) {
      fp16x8 bb = *(const fp16x8*)&Bu[jt * 16 + l16][kk * 32 + quad * 8];
      acc[jt] = __builtin_amdgcn_mfma_f32_16x16x32_f16(a, bb, acc[jt], 0, 0, 0);
    }
  }
#pragma unroll
  for (int jt = 0; jt < 8; jt++) {
    int j = j0 + jt * 16 + l16;
    fp16x4 o;
#pragma unroll
    for (int r = 0; r < 4; r++) o[r] = (f16_t)acc[jt][r];
    *(fp16x4*)&St[(size_t)h * UH + (size_t)j * CHUNK + m0 + quad * 4] = o;
  }
}

// ---------------- prefix over chunks: local end-states -> carry-in states ----------------
__global__ __launch_bounds__(256) void scan_prefix2(
    f16_t* __restrict__ St,
    const float* __restrict__ wSre, const float* __restrict__ wSim) {
  int gid = blockIdx.x * 256 + threadIdx.x;  // (h*16 + b)*32 + n
  if (gid >= Hc * Bq * N2) return;
  int n = gid & 31;
  int b = (gid >> 5) & 15;
  int h = gid >> 9;
  float wr = wSre[h * N2 + n], wi = wSim[h * N2 + n];
  float cr = 0.f, ci = 0.f;
  unsigned* base = (unsigned*)(St + (size_t)h * UH + (size_t)b * Tt + 2 * n);
  for (int c = 0; c < NCH; c++) {
    union { unsigned u; f16_t h2[2]; } in, out;
    in.u = base[c * 32];
    float sre = (float)in.h2[0], sim = (float)in.h2[1];
    out.h2[0] = (f16_t)cr; out.h2[1] = (f16_t)ci;
    base[c * 32] = out.u;
    float c0 = cr;
    cr = fmaf(wr, c0, fmaf(-wi, ci, sre));
    ci = fmaf(wr, ci, fmaf(wi, c0, sim));
  }
}

// ---------------- out GEMM: Y = gelu([T|V].[U;S0] + D*u), bf16 out [h][j][tau] ----------------
__global__ __launch_bounds__(256) void gemm_out(
    const f16_t* __restrict__ U, const f16_t* __restrict__ Ag,
    const f16_t* __restrict__ St, const float* __restrict__ Dv,
    unsigned short* __restrict__ Yb) {
  __shared__ f16_t Aa[64][136];
  __shared__ f16_t Bb[128][136];
  int tid = threadIdx.x;
  int j0 = blockIdx.x * 128, h = blockIdx.y;
#pragma unroll
  for (int p = 0; p < 4; p++) {
    int idx = p * 256 + tid;
    int row = idx >> 4, c8 = (idx & 15) * 8;
    *(fp16x8*)&Aa[row][c8] = *(const fp16x8*)&Ag[(size_t)h * 8192 + row * 128 + c8];
  }
#pragma unroll
  for (int p = 0; p < 4; p++) {
    int idx = p * 256 + tid;
    int row = idx >> 3, c8 = (idx & 7) * 8;
    *(fp16x8*)&Bb[row][c8] =
        *(const fp16x8*)&U[(size_t)h * UH + (size_t)(j0 + row) * CHUNK + c8];
    *(fp16x8*)&Bb[row][64 + c8] =
        *(const fp16x8*)&St[(size_t)h * UH + (size_t)(j0 + row) * CHUNK + c8];
  }
  __syncthreads();
  int wave = tid >> 6, lane = tid & 63, l16 = lane & 15, quad = lane >> 4;
  int m0 = wave * 16;
  floatx4 acc[8];
#pragma unroll
  for (int jt = 0; jt < 8; jt++) acc[jt] = (floatx4){0.f, 0.f, 0.f, 0.f};
#pragma unroll
  for (int kk = 0; kk < 4; kk++) {
    fp16x8 a = *(const fp16x8*)&Aa[m0 + l16][kk * 32 + quad * 8];
#pragma unroll
    for (int jt = 0; jt < 8; jt++) {
      fp16x8 bb = *(const fp16x8*)&Bb[jt * 16 + l16][kk * 32 + quad * 8];
      acc[jt] = __builtin_amdgcn_mfma_f32_16x16x32_f16(a, bb, acc[jt], 0, 0, 0);
    }
  }
  float d = Dv[h];
  int tb = m0 + quad * 4;
#pragma unroll
  for (int jt = 0; jt < 8; jt++) {
    int jr = jt * 16 + l16;
    fp16x4 u4 = *(const fp16x4*)&Bb[jr][tb];
    ushort4 o;
#pragma unroll
    for (int r = 0; r < 4; r++) {
      float v = fmaf(d, (float)u4[r], acc[jt][r]);
      v = 0.5f * v * (1.0f + erff(v * 0.70710678118654752f));
      ((unsigned short*)&o)[r] = bfbits(v);
    }
    *(ushort4*)&Yb[(size_t)h * UH + (size_t)(j0 + jr) * CHUNK + tb] = o;
  }
}

// ---------------- unpack: Yb[h][j][tau] bf16 -> ybf (B,T,C) bf16 ----------------
__global__ __launch_bounds__(256) void unpack_y(const unsigned short* __restrict__ Yb,
                                                unsigned short* __restrict__ yb) {
  __shared__ unsigned short tile[64][65];
  int tid = threadIdx.x;
  int t0 = blockIdx.x * 64, h0 = blockIdx.y * 64, b = blockIdx.z;
#pragma unroll
  for (int p = 0; p < 2; p++) {
    int idx = p * 256 + tid;
    int hr = idx >> 3, g = (idx & 7) * 8;
    uint4 v = *(const uint4*)&Yb[(size_t)(h0 + hr) * UH + (size_t)b * Tt + t0 + g];
    const unsigned short* s = (const unsigned short*)&v;
#pragma unroll
    for (int i = 0; i < 8; i++) tile[hr][g + i] = s[i];
  }
  __syncthreads();
#pragma unroll
  for (int p = 0; p < 2; p++) {
    int idx = p * 256 + tid;
    int tr = idx >> 3, g = (idx & 7) * 8;
    unsigned short o[8];
#pragma unroll
    for (int i = 0; i < 8; i++) o[i] = tile[g + i][tr];
    *(uint4*)&yb[((size_t)(b * Tt + t0 + tr)) * Hc + h0 + g] = *(uint4*)o;
  }
}

// ---------------- MFMA GEMM: out(B,T,N) = act(B,T,K) x W(N,K)^T, bf16 out ----------------
// (R4 structure: reg-staged, loads issued at loop top, 2 barriers/k-step.)
// EPI 0: outb = bf16(acc + bias)
// EPI 1: outb = bf16(relu(acc + bias) * mask)
// EPI 2: GLU, W has 2N rows: outb = bf16((a+ba)*sigmoid(g+bg))
template <int EPI>
__global__ __launch_bounds__(256) void mfma_gemm(
    const __bf16* __restrict__ act, const __bf16* __restrict__ W,
    const float* __restrict__ bias, const float* __restrict__ mask,
    unsigned short* __restrict__ outb, int K, int NOUT) {
  __shared__ __bf16 As[128][32];
  __shared__ __bf16 Bs[128][32];
  __shared__ __bf16 Bs2[(EPI == 2) ? 128 : 1][32];
  int tid = threadIdx.x;
  int b = blockIdx.z;
  int t0 = blockIdx.x * 128, n0 = blockIdx.y * 128;
  int wave = tid >> 6, lane = tid & 63, l16 = lane & 15, quad = lane >> 4;
  int wm = wave >> 1, wn = wave & 1;
  int sr = tid >> 2, sk = (tid & 3) * 8;

  floatx4 acc[4][4];
  floatx4 accg[(EPI == 2) ? 4 : 1][4];
#pragma unroll
  for (int i = 0; i < 4; i++)
#pragma unroll
    for (int j = 0; j < 4; j++) {
      acc[i][j] = (floatx4){0.f, 0.f, 0.f, 0.f};
      if constexpr (EPI == 2) accg[i][j] = (floatx4){0.f, 0.f, 0.f, 0.f};
    }

  const __bf16* aPtr = act + ((size_t)(b * Tt + t0 + sr)) * K + sk;
  const __bf16* bPtr = W + (size_t)(n0 + sr) * K + sk;
  const __bf16* gPtr = (EPI == 2) ? (W + (size_t)(NOUT + n0 + sr) * K + sk) : bPtr;

  for (int k0 = 0; k0 < K; k0 += 32) {
    uint4 a0 = *(const uint4*)(aPtr + k0);
    uint4 a1 = *(const uint4*)(aPtr + k0 + (size_t)64 * K);
    uint4 w0 = *(const uint4*)(bPtr + k0);
    uint4 w1 = *(const uint4*)(bPtr + k0 + (size_t)64 * K);
    uint4 g0, g1;
    if constexpr (EPI == 2) {
      g0 = *(const uint4*)(gPtr + k0);
      g1 = *(const uint4*)(gPtr + k0 + (size_t)64 * K);
    }
    __syncthreads();
    *(uint4*)&As[sr][sk] = a0; *(uint4*)&As[sr + 64][sk] = a1;
    *(uint4*)&Bs[sr][sk] = w0; *(uint4*)&Bs[sr + 64][sk] = w1;
    if constexpr (EPI == 2) { *(uint4*)&Bs2[sr][sk] = g0; *(uint4*)&Bs2[sr + 64][sk] = g1; }
    __syncthreads();
    bf16x8 af[4], bfr[4], gfr[(EPI == 2) ? 4 : 1];
#pragma unroll
    for (int i = 0; i < 4; i++)
      af[i] = *(const bf16x8*)&As[wm * 64 + i * 16 + l16][quad * 8];
#pragma unroll
    for (int j = 0; j < 4; j++) {
      bfr[j] = *(const bf16x8*)&Bs[wn * 64 + j * 16 + l16][quad * 8];
      if constexpr (EPI == 2)
        gfr[j] = *(const bf16x8*)&Bs2[wn * 64 + j * 16 + l16][quad * 8];
    }
#pragma unroll
    for (int i = 0; i < 4; i++)
#pragma unroll
      for (int j = 0; j < 4; j++) {
        acc[i][j] = __builtin_amdgcn_mfma_f32_16x16x32_bf16(af[i], bfr[j], acc[i][j], 0, 0, 0);
        if constexpr (EPI == 2)
          accg[i][j] = __builtin_amdgcn_mfma_f32_16x16x32_bf16(af[i], gfr[j], accg[i][j], 0, 0, 0);
      }
  }

  // epilogue: D row = t (i*16 + quad*4 + r), col = n (j*16 + l16)
#pragma unroll
  for (int i = 0; i < 4; i++) {
    int tb = t0 + wm * 64 + i * 16 + quad * 4;
    float mv[4];
    if constexpr (EPI == 1) {
#pragma unroll
      for (int r = 0; r < 4; r++) mv[r] = mask[(size_t)b * Tt + tb + r];
    }
#pragma unroll
    for (int j = 0; j < 4; j++) {
      int n = n0 + wn * 64 + j * 16 + l16;
      float bn = bias[n];
      float bg = (EPI == 2) ? bias[NOUT + n] : 0.f;
#pragma unroll
      for (int r = 0; r < 4; r++) {
        size_t o = ((size_t)(b * Tt + tb + r)) * NOUT + n;
        if constexpr (EPI == 0) {
          outb[o] = bfbits(acc[i][j][r] + bn);
        } else if constexpr (EPI == 1) {
          float v = fmaxf(acc[i][j][r] + bn, 0.f) * mv[r];
          outb[o] = bfbits(v);
        } else {
          float a = acc[i][j][r] + bn;
          float g = accg[i][j][r] + bg;
          outb[o] = bfbits(a / (1.f + expf(-g)));
        }
      }
    }
  }
}

// ---------------- LayerNorm over C: out = LN(in1*f1 + bf16(in2)*f2) ----------------
__global__ __launch_bounds__(256) void ln_t(
    const float* __restrict__ in1, const unsigned short* __restrict__ in2b,
    const float* __restrict__ mask, const float* __restrict__ gamma,
    const float* __restrict__ beta, float* __restrict__ out,
    unsigned short* __restrict__ outb, int m1, int m2) {
  int row = blockIdx.x * 4 + (threadIdx.x >> 6);  // b*Tt + t
  int lane = threadIdx.x & 63;
  float mv = mask[row];
  float f1 = m1 ? mv : 1.f;
  float f2 = m2 ? mv : 1.f;
  size_t base = (size_t)row * Hc;
  float v[6], sum = 0.f, sq = 0.f;
#pragma unroll
  for (int j = 0; j < 6; j++) {
    int idx = lane + 64 * j;
    float a = in1[base + idx] * f1 + bf2f(in2b[base + idx]) * f2;
    v[j] = a; sum += a; sq = fmaf(a, a, sq);
  }
#pragma unroll
  for (int off = 32; off >= 1; off >>= 1) {
    sum += __shfl_xor(sum, off, 64);
    sq  += __shfl_xor(sq,  off, 64);
  }
  float m = sum * (1.f / Hc);
  float var = sq * (1.f / Hc) - m * m;
  float rs = rsqrtf(var + 1e-4f);
#pragma unroll
  for (int j = 0; j < 6; j++) {
    int idx = lane + 64 * j;
    float o = (v[j] - m) * rs * gamma[idx] + beta[idx];
    out[base + idx] = o;
    if (outb) outb[base + idx] = bfbits(o * mv);
  }
}

// ---------------- diagnostic ----------------
__global__ void diag_kernel(float* out, float v) {
  if (blockIdx.x == 0 && threadIdx.x == 0) out[0] = v;
}

extern "C" void kernel_launch(void* const* d_in, const int* in_sizes, int n_in,
                              void* d_out, int out_size, void* d_ws, size_t ws_size,
                              hipStream_t stream) {
  const float* x_in  = (const float*)d_in[0];
  const float* xmask = (const float*)d_in[1];
  const float* log_dt = (const float*)d_in[2];
  const float* A_re = (const float*)d_in[3];
  const float* A_im = (const float*)d_in[4];
  const float* C_re = (const float*)d_in[5];
  const float* C_im = (const float*)d_in[6];
  const float* Dv   = (const float*)d_in[7];
  const float* Wout = (const float*)d_in[8];
  const float* bout = (const float*)d_in[9];
  const float* g1   = (const float*)d_in[10];
  const float* be1  = (const float*)d_in[11];
  const float* W1   = (const float*)d_in[12];
  const float* bf1  = (const float*)d_in[13];
  const float* W2   = (const float*)d_in[14];
  const float* bf2  = (const float*)d_in[15];
  const float* g2   = (const float*)d_in[16];
  const float* be2  = (const float*)d_in[17];

  const size_t NXf   = (size_t)Bq * Hc * Tt;          // 12,582,912 floats
  const size_t NP    = (size_t)LYR * Hc * N2;         // 73,728
  const size_t YBFf  = NXf / 2;                       // bf16 y / x1b region, in floats
  const size_t HBFf  = (size_t)Bq * Tt * HFq / 2;     // bf16 h region, in floats
  const size_t WOUTf = (size_t)LYR * TWOH * Hc / 2;
  const size_t W1f   = (size_t)LYR * HFq * Hc / 2;
  const size_t W2f   = (size_t)LYR * Hc * HFq / 2;

  size_t need = 2 * NXf + YBFf + HBFf + WOUTf + W1f + W2f + 6 * NP;
  if (ws_size / 4 < need) {
    diag_kernel<<<1, 64, 0, stream>>>((float*)d_out, 1000.0f + (float)(ws_size >> 20));
    return;
  }

  float* ws = (float*)d_ws;
  float* xT   = ws;                       // (B,T,C) fp32 layer state
  float* tmp  = xT + NXf;                 // first half: U fp16 overlay; second half: tmpb bf16
  float* ybfF = tmp + NXf;                // bf16 (B,T,C): y, then x1*mask
  float* hbfF = ybfF + YBFf;              // bf16 (B,T,HF): ffn hidden; scan overlays
  float* wobF = hbfF + HBFf;              // bf16 weights
  float* w1bF = wobF + WOUTf;
  float* w2bF = w1bF + W1f;
  float* wre  = w2bF + W2f;
  float* wim  = wre + NP;
  float* cdre = wim + NP;
  float* cdim = cdre + NP;
  float* wSre = cdim + NP;
  float* wSim = wSre + NP;

  unsigned short* ybf = (unsigned short*)ybfF;
  unsigned short* hbf = (unsigned short*)hbfF;
  unsigned short* wob = (unsigned short*)wobF;
  unsigned short* w1b = (unsigned short*)w1bF;
  unsigned short* w2b = (unsigned short*)w2bF;
  float* x1 = (float*)d_out;              // (B,T,C) fp32 post-LN1 lives in d_out

  // scan overlays: U in tmp first half; tmpb bf16 in second half (disjoint);
  // St/Yb/mats in hbf region (dead until FFN)
  f16_t* Ub   = (f16_t*)tmp;                                  // 12.58M fp16 = 6.29M fl
  unsigned short* tmpb = (unsigned short*)(tmp + NXf / 2);    // 12.58M bf16
  f16_t* St16 = (f16_t*)hbfF;                                 // 12.58M fp16
  unsigned short* Ybi = (unsigned short*)(hbfF + YBFf);       // 12.58M bf16
  f16_t* Ag   = (f16_t*)(hbfF + 2 * YBFf);                    // 384*8192 fp16
  f16_t* Wg   = Ag + (size_t)384 * 8192;                      // 384*4096 fp16

  param_kernel<<<(LYR * Hc * N2 + 255) / 256, 256, 0, stream>>>(
      log_dt, A_re, A_im, C_re, C_im, wre, wim, cdre, cdim, wSre, wSim);
  cvt_bf16_kernel<<<(int)(2 * WOUTf + 1023) / 1024, 256, 0, stream>>>(Wout, wob, (int)(WOUTf / 2));
  cvt_bf16_kernel<<<(int)(2 * W1f + 1023) / 1024, 256, 0, stream>>>(W1, w1b, (int)(W1f / 2));
  cvt_bf16_kernel<<<(int)(2 * W2f + 1023) / 1024, 256, 0, stream>>>(W2, w2b, (int)(W2f / 2));
  transpose_fwd<<<dim3(Tt / 32, Hc / 32, Bq), dim3(32, 8), 0, stream>>>(x_in, xT);

  for (int i = 0; i < LYR; i++) {
    size_t po = (size_t)i * Hc * N2;

    // --- S4D scan via MFMA (chunked Toeplitz + carry) ---
    pack_u<<<dim3(Tt / 64, Hc / 64, Bq), 256, 0, stream>>>(xT, xmask, Ub);
    build_mats<<<Hc, 256, 0, stream>>>(wre + po, wim + po, cdre + po, cdim + po, Ag, Wg);
    gemm_state<<<dim3(NJ / 128, Hc), 256, 0, stream>>>(Ub, Wg, St16);
    scan_prefix2<<<(Hc * Bq * N2) / 256, 256, 0, stream>>>(St16, wSre + po, wSim + po);
    gemm_out<<<dim3(NJ / 128, Hc), 256, 0, stream>>>(Ub, Ag, St16, Dv + (size_t)i * Hc, Ybi);
    unpack_y<<<dim3(Tt / 64, Hc / 64, Bq), 256, 0, stream>>>(Ybi, ybf);

    // glu = bf16(GLU(Wout*y + bout)) -> tmpb
    mfma_gemm<2><<<dim3(Tt / 128, Hc / 128, Bq), 256, 0, stream>>>(
        (const __bf16*)ybf, (const __bf16*)(wob + (size_t)i * TWOH * Hc),
        bout + (size_t)i * TWOH, xmask, tmpb, Hc, Hc);

    // x1 = LN(x*mask + glu) -> d_out fp32 ; x1b = bf16(x1*mask) -> ybf
    ln_t<<<(Bq * Tt) / 4, 256, 0, stream>>>(
        xT, tmpb, xmask, g1 + (size_t)i * Hc, be1 + (size_t)i * Hc, x1, ybf, 1, 0);

    // h = bf16(relu(W1*x1b + bf1) * mask) -> hbf
    mfma_gemm<1><<<dim3(Tt / 128, HFq / 128, Bq), 256, 0, stream>>>(
        (const __bf16*)ybf, (const __bf16*)(w1b + (size_t)i * HFq * Hc),
        bf1 + (size_t)i * HFq, xmask, hbf, Hc, HFq);

    // f = bf16(W2*h + bf2) -> tmpb
    mfma_gemm<0><<<dim3(Tt / 128, Hc / 128, Bq), 256, 0, stream>>>(
        (const __bf16*)hbf, (const __bf16*)(w2b + (size_t)i * Hc * HFq),
        bf2 + (size_t)i * Hc, xmask, tmpb, HFq, Hc);

    // x = LN(x1 + f*mask) -> xT
    ln_t<<<(Bq * Tt) / 4, 256, 0, stream>>>(
        x1, tmpb, xmask, g2 + (size_t)i * Hc, be2 + (size_t)i * Hc, xT, nullptr, 0, 1);
  }

  transpose_bwd<<<dim3(Tt / 32, Hc / 32, Bq), dim3(32, 8), 0, stream>>>(xT, xmask, (float*)d_out);
}

// Round 8
// 1900.587 us; speedup vs baseline: 1.1261x; 1.0458x over previous
//
#include <hip/hip_runtime.h>
#include <math.h>

#define Bq 16
#define Hc 384
#define Tt 2048
#define N2 32
#define LYR 6
#define HFq 1536
#define TWOH 768
#define CHUNK 64
#define NCH (Tt/CHUNK)   // 32
#define NJ (Bq*NCH)      // 512 chunk-columns per head
#define UH (NJ*CHUNK)    // 32768 elements per head in U/St/Y layouts

typedef __bf16 bf16x8 __attribute__((ext_vector_type(8)));
typedef float floatx4 __attribute__((ext_vector_type(4)));
typedef _Float16 f16_t;
typedef f16_t fp16x8 __attribute__((ext_vector_type(8)));
typedef f16_t fp16x4 __attribute__((ext_vector_type(4)));

__device__ __forceinline__ unsigned short bfbits(float f) {
  union { float f; unsigned u; } x; x.f = f;
  return (unsigned short)((x.u + 0x7FFF + ((x.u >> 16) & 1)) >> 16);
}
__device__ __forceinline__ float bf2f(unsigned short u) {
  union { unsigned u; float f; } x; x.u = ((unsigned)u) << 16; return x.f;
}

// async global->LDS, 16B per lane; dest is wave-uniform base, HW writes lane i
// at base + i*16B (linear). Source address is per-lane.
__device__ __forceinline__ void gl_lds16(const void* g, void* l) {
  __builtin_amdgcn_global_load_lds(
      (const __attribute__((address_space(1))) void*)g,
      (__attribute__((address_space(3))) void*)l, 16, 0, 0);
}

// ---------------- param precompute (fp64 for accuracy) ----------------
__global__ void param_kernel(const float* __restrict__ log_dt,
                             const float* __restrict__ A_re, const float* __restrict__ A_im,
                             const float* __restrict__ C_re, const float* __restrict__ C_im,
                             float* __restrict__ wre, float* __restrict__ wim,
                             float* __restrict__ cdre, float* __restrict__ cdim,
                             float* __restrict__ wSre, float* __restrict__ wSim) {
  int idx = blockIdx.x * blockDim.x + threadIdx.x;
  if (idx >= LYR * Hc * N2) return;
  int hn = idx / N2;
  double dt = exp((double)log_dt[hn]);
  double are = (double)A_re[idx], aim = (double)A_im[idx];
  double dre = are * dt, dimv = aim * dt;
  double er = exp(dre);
  double wr = er * cos(dimv), wi_ = er * sin(dimv);
  double den = are * are + aim * aim;
  double nr = wr - 1.0, ni = wi_;
  double qr = (nr * are + ni * aim) / den;
  double qi = (ni * are - nr * aim) / den;
  double cr = (double)C_re[idx], ci = (double)C_im[idx];
  cdre[idx] = (float)(2.0 * (cr * qr - ci * qi));
  cdim[idx] = (float)(2.0 * (cr * qi + ci * qr));
  wre[idx] = (float)wr; wim[idx] = (float)wi_;
  double es = exp(dre * (double)CHUNK);
  wSre[idx] = (float)(es * cos(dimv * (double)CHUNK));
  wSim[idx] = (float)(es * sin(dimv * (double)CHUNK));
}

// ---------------- weight fp32 -> bf16 (RNE) ----------------
__global__ void cvt_bf16_kernel(const float* __restrict__ in, unsigned short* __restrict__ out,
                                int n4) {
  int idx = blockIdx.x * 256 + threadIdx.x;
  if (idx >= n4) return;
  float4 v = ((const float4*)in)[idx];
  ushort4 o;
  o.x = bfbits(v.x); o.y = bfbits(v.y); o.z = bfbits(v.z); o.w = bfbits(v.w);
  ((ushort4*)out)[idx] = o;
}

// ---------------- transpose (B,C,T) -> (B,T,C) ----------------
__global__ __launch_bounds__(256) void transpose_fwd(const float* __restrict__ in,
                                                     float* __restrict__ out) {
  __shared__ float tile[32][33];
  int tx = threadIdx.x, ty = threadIdx.y;
  int t0 = blockIdx.x * 32, c0 = blockIdx.y * 32, b = blockIdx.z;
#pragma unroll
  for (int k = 0; k < 4; k++)
    tile[ty + 8 * k][tx] = in[((size_t)(b * Hc + c0 + ty + 8 * k)) * Tt + t0 + tx];
  __syncthreads();
#pragma unroll
  for (int k = 0; k < 4; k++)
    out[((size_t)(b * Tt + t0 + ty + 8 * k)) * Hc + c0 + tx] = tile[tx][ty + 8 * k];
}

// ---------------- transpose (B,T,C) -> (B,C,T) with mask ----------------
__global__ __launch_bounds__(256) void transpose_bwd(const float* __restrict__ in,
                                                     const float* __restrict__ mask,
                                                     float* __restrict__ out) {
  __shared__ float tile[32][33];
  int tx = threadIdx.x, ty = threadIdx.y;
  int t0 = blockIdx.x * 32, c0 = blockIdx.y * 32, b = blockIdx.z;
#pragma unroll
  for (int k = 0; k < 4; k++)
    tile[ty + 8 * k][tx] = in[((size_t)(b * Tt + t0 + ty + 8 * k)) * Hc + c0 + tx];
  __syncthreads();
  float mv = mask[(size_t)b * Tt + t0 + tx];
#pragma unroll
  for (int k = 0; k < 4; k++)
    out[((size_t)(b * Hc + c0 + ty + 8 * k)) * Tt + t0 + tx] = tile[tx][ty + 8 * k] * mv;
}

// ---------------- pack: xT (B,T,C) fp32 * mask -> U[h][j][tau] fp16 ----------------
__global__ __launch_bounds__(256) void pack_u(const float* __restrict__ xT,
                                              const float* __restrict__ mask,
                                              f16_t* __restrict__ U) {
  __shared__ float tile[64][65];
  int tid = threadIdx.x;
  int t0 = blockIdx.x * 64, h0 = blockIdx.y * 64, b = blockIdx.z;
#pragma unroll
  for (int p = 0; p < 4; p++) {
    int idx = p * 256 + tid;
    int row = idx >> 4, c4 = (idx & 15) * 4;
    float4 v = *(const float4*)&xT[((size_t)(b * Tt + t0 + row)) * Hc + h0 + c4];
    float mv = mask[(size_t)b * Tt + t0 + row];
    tile[row][c4] = v.x * mv; tile[row][c4 + 1] = v.y * mv;
    tile[row][c4 + 2] = v.z * mv; tile[row][c4 + 3] = v.w * mv;
  }
  __syncthreads();
#pragma unroll
  for (int p = 0; p < 2; p++) {
    int idx = p * 256 + tid;
    int hr = idx >> 3, g = (idx & 7) * 8;
    fp16x8 o;
#pragma unroll
    for (int i = 0; i < 8; i++) o[i] = (f16_t)tile[g + i][hr];
    *(fp16x8*)&U[(size_t)(h0 + hr) * UH + (size_t)b * Tt + t0 + g] = o;
  }
}

// ---------------- build per-head matrices: Ag = [T | V] (64x128), Wg (64x64) ----------------
__global__ __launch_bounds__(256) void build_mats(
    const float* __restrict__ wre, const float* __restrict__ wim,
    const float* __restrict__ cdre, const float* __restrict__ cdim,
    f16_t* __restrict__ Ag, f16_t* __restrict__ Wg) {
  __shared__ float pre[65][32], pim[65][32], Kc[64], cdr_s[32], cdi_s[32];
  int h = blockIdx.x, tid = threadIdx.x;
  if (tid < 32) {
    float wr = wre[h * N2 + tid], wi = wim[h * N2 + tid];
    cdr_s[tid] = cdre[h * N2 + tid];
    cdi_s[tid] = cdim[h * N2 + tid];
    float pr = 1.f, pi = 0.f;
    for (int p = 0; p <= 64; p++) {
      pre[p][tid] = pr; pim[p][tid] = pi;
      float nr2 = pr * wr - pi * wi;
      pi = pr * wi + pi * wr;
      pr = nr2;
    }
  }
  __syncthreads();
  if (tid < 64) {
    float s = 0.f;
    for (int n = 0; n < 32; n++)
      s = fmaf(cdr_s[n], pre[tid][n], fmaf(-cdi_s[n], pim[tid][n], s));
    Kc[tid] = s;
  }
  __syncthreads();
  for (int i = tid; i < 64 * 128; i += 256) {
    int m = i >> 7, k = i & 127;
    float v;
    if (k < 64) {
      v = (m >= k) ? Kc[m - k] : 0.f;
    } else {
      int kk = k - 64, n = kk >> 1;
      v = (kk & 1) ? -fmaf(cdr_s[n], pim[m + 1][n], cdi_s[n] * pre[m + 1][n])
                   :  fmaf(cdr_s[n], pre[m + 1][n], -cdi_s[n] * pim[m + 1][n]);
    }
    Ag[(size_t)h * 8192 + i] = (f16_t)v;
  }
  for (int i = tid; i < 64 * 64; i += 256) {
    int m = i >> 6, tau = i & 63, n = m >> 1;
    float v = (m & 1) ? pim[63 - tau][n] : pre[63 - tau][n];
    Wg[(size_t)h * 4096 + i] = (f16_t)v;
  }
}

// ---------------- state GEMM: S_end[m'][j] = Wg . U  (per head), fp16 out ----------------
__global__ __launch_bounds__(256) void gemm_state(const f16_t* __restrict__ U,
                                                  const f16_t* __restrict__ Wg,
                                                  f16_t* __restrict__ St) {
  __shared__ f16_t Aw[64][72];
  __shared__ f16_t Bu[128][72];
  int tid = threadIdx.x;
  int j0 = blockIdx.x * 128, h = blockIdx.y;
#pragma unroll
  for (int p = 0; p < 2; p++) {
    int idx = p * 256 + tid;
    int row = idx >> 3, c8 = (idx & 7) * 8;
    *(fp16x8*)&Aw[row][c8] = *(const fp16x8*)&Wg[(size_t)h * 4096 + row * 64 + c8];
  }
#pragma unroll
  for (int p = 0; p < 4; p++) {
    int idx = p * 256 + tid;
    int row = idx >> 3, c8 = (idx & 7) * 8;
    *(fp16x8*)&Bu[row][c8] =
        *(const fp16x8*)&U[(size_t)h * UH + (size_t)(j0 + row) * CHUNK + c8];
  }
  __syncthreads();
  int wave = tid >> 6, lane = tid & 63, l16 = lane & 15, quad = lane >> 4;
  int m0 = wave * 16;
  floatx4 acc[8];
#pragma unroll
  for (int jt = 0; jt < 8; jt++) acc[jt] = (floatx4){0.f, 0.f, 0.f, 0.f};
#pragma unroll
  for (int kk = 0; kk < 2; kk++) {
    fp16x8 a = *(const fp16x8*)&Aw[m0 + l16][kk * 32 + quad * 8];
#pragma unroll
    for (int jt = 0; jt < 8; jt++) {
      fp16x8 bb = *(const fp16x8*)&Bu[jt * 16 + l16][kk * 32 + quad * 8];
      acc[jt] = __builtin_amdgcn_mfma_f32_16x16x32_f16(a, bb, acc[jt], 0, 0, 0);
    }
  }
#pragma unroll
  for (int jt = 0; jt < 8; jt++) {
    int j = j0 + jt * 16 + l16;
    fp16x4 o;
#pragma unroll
    for (int r = 0; r < 4; r++) o[r] = (f16_t)acc[jt][r];
    *(fp16x4*)&St[(size_t)h * UH + (size_t)j * CHUNK + m0 + quad * 4] = o;
  }
}

// ---------------- prefix over chunks: local end-states -> carry-in states ----------------
__global__ __launch_bounds__(256) void scan_prefix2(
    f16_t* __restrict__ St,
    const float* __restrict__ wSre, const float* __restrict__ wSim) {
  int gid = blockIdx.x * 256 + threadIdx.x;  // (h*16 + b)*32 + n
  if (gid >= Hc * Bq * N2) return;
  int n = gid & 31;
  int b = (gid >> 5) & 15;
  int h = gid >> 9;
  float wr = wSre[h * N2 + n], wi = wSim[h * N2 + n];
  float cr = 0.f, ci = 0.f;
  unsigned* base = (unsigned*)(St + (size_t)h * UH + (size_t)b * Tt + 2 * n);
  for (int c = 0; c < NCH; c++) {
    union { unsigned u; f16_t h2[2]; } in, out;
    in.u = base[c * 32];
    float sre = (float)in.h2[0], sim = (float)in.h2[1];
    out.h2[0] = (f16_t)cr; out.h2[1] = (f16_t)ci;
    base[c * 32] = out.u;
    float c0 = cr;
    cr = fmaf(wr, c0, fmaf(-wi, ci, sre));
    ci = fmaf(wr, ci, fmaf(wi, c0, sim));
  }
}

// ---------------- out GEMM: Y = gelu([T|V].[U;S0] + D*u), bf16 out [h][j][tau] ----------------
__global__ __launch_bounds__(256) void gemm_out(
    const f16_t* __restrict__ U, const f16_t* __restrict__ Ag,
    const f16_t* __restrict__ St, const float* __restrict__ Dv,
    unsigned short* __restrict__ Yb) {
  __shared__ f16_t Aa[64][136];
  __shared__ f16_t Bb[128][136];
  int tid = threadIdx.x;
  int j0 = blockIdx.x * 128, h = blockIdx.y;
#pragma unroll
  for (int p = 0; p < 4; p++) {
    int idx = p * 256 + tid;
    int row = idx >> 4, c8 = (idx & 15) * 8;
    *(fp16x8*)&Aa[row][c8] = *(const fp16x8*)&Ag[(size_t)h * 8192 + row * 128 + c8];
  }
#pragma unroll
  for (int p = 0; p < 4; p++) {
    int idx = p * 256 + tid;
    int row = idx >> 3, c8 = (idx & 7) * 8;
    *(fp16x8*)&Bb[row][c8] =
        *(const fp16x8*)&U[(size_t)h * UH + (size_t)(j0 + row) * CHUNK + c8];
    *(fp16x8*)&Bb[row][64 + c8] =
        *(const fp16x8*)&St[(size_t)h * UH + (size_t)(j0 + row) * CHUNK + c8];
  }
  __syncthreads();
  int wave = tid >> 6, lane = tid & 63, l16 = lane & 15, quad = lane >> 4;
  int m0 = wave * 16;
  floatx4 acc[8];
#pragma unroll
  for (int jt = 0; jt < 8; jt++) acc[jt] = (floatx4){0.f, 0.f, 0.f, 0.f};
#pragma unroll
  for (int kk = 0; kk < 4; kk++) {
    fp16x8 a = *(const fp16x8*)&Aa[m0 + l16][kk * 32 + quad * 8];
#pragma unroll
    for (int jt = 0; jt < 8; jt++) {
      fp16x8 bb = *(const fp16x8*)&Bb[jt * 16 + l16][kk * 32 + quad * 8];
      acc[jt] = __builtin_amdgcn_mfma_f32_16x16x32_f16(a, bb, acc[jt], 0, 0, 0);
    }
  }
  float d = Dv[h];
  int tb = m0 + quad * 4;
#pragma unroll
  for (int jt = 0; jt < 8; jt++) {
    int jr = jt * 16 + l16;
    fp16x4 u4 = *(const fp16x4*)&Bb[jr][tb];
    ushort4 o;
#pragma unroll
    for (int r = 0; r < 4; r++) {
      float v = fmaf(d, (float)u4[r], acc[jt][r]);
      v = 0.5f * v * (1.0f + erff(v * 0.70710678118654752f));
      ((unsigned short*)&o)[r] = bfbits(v);
    }
    *(ushort4*)&Yb[(size_t)h * UH + (size_t)(j0 + jr) * CHUNK + tb] = o;
  }
}

// ---------------- unpack: Yb[h][j][tau] bf16 -> ybf (B,T,C) bf16 ----------------
__global__ __launch_bounds__(256) void unpack_y(const unsigned short* __restrict__ Yb,
                                                unsigned short* __restrict__ yb) {
  __shared__ unsigned short tile[64][65];
  int tid = threadIdx.x;
  int t0 = blockIdx.x * 64, h0 = blockIdx.y * 64, b = blockIdx.z;
#pragma unroll
  for (int p = 0; p < 2; p++) {
    int idx = p * 256 + tid;
    int hr = idx >> 3, g = (idx & 7) * 8;
    uint4 v = *(const uint4*)&Yb[(size_t)(h0 + hr) * UH + (size_t)b * Tt + t0 + g];
    const unsigned short* s = (const unsigned short*)&v;
#pragma unroll
    for (int i = 0; i < 8; i++) tile[hr][g + i] = s[i];
  }
  __syncthreads();
#pragma unroll
  for (int p = 0; p < 2; p++) {
    int idx = p * 256 + tid;
    int tr = idx >> 3, g = (idx & 7) * 8;
    unsigned short o[8];
#pragma unroll
    for (int i = 0; i < 8; i++) o[i] = tile[g + i][tr];
    *(uint4*)&yb[((size_t)(b * Tt + t0 + tr)) * Hc + h0 + g] = *(uint4*)o;
  }
}

// ---------------- MFMA GEMM: out(B,T,N) = act(B,T,K) x W(N,K)^T, bf16 out ----------------
// T3 minimum-2-phase: global_load_lds staging + DOUBLE-BUFFERED LDS, one barrier
// per k-step. Prefetch of tile t+1 is issued BEFORE the MFMAs of tile t, so the
// barrier's vmcnt drain finds the loads already covered by 16 MFMA + 8 ds_read.
// EPI 0: outb = bf16(acc + bias)
// EPI 1: outb = bf16(relu(acc + bias) * mask)
// EPI 2: GLU, W has 2N rows: outb = bf16((a+ba)*sigmoid(g+bg))
template <int EPI>
__global__ __launch_bounds__(256) void mfma_gemm(
    const __bf16* __restrict__ act, const __bf16* __restrict__ W,
    const float* __restrict__ bias, const float* __restrict__ mask,
    unsigned short* __restrict__ outb, int K, int NOUT) {
  __shared__ __bf16 As[2][128][32];
  __shared__ __bf16 Bs[2][128][32];
  __shared__ __bf16 Bs2[(EPI == 2) ? 2 : 1][(EPI == 2) ? 128 : 1][32];
  int tid = threadIdx.x;
  int b = blockIdx.z;
  int t0 = blockIdx.x * 128, n0 = blockIdx.y * 128;
  int wave = tid >> 6, lane = tid & 63, l16 = lane & 15, quad = lane >> 4;
  int wm = wave >> 1, wn = wave & 1;

  floatx4 acc[4][4];
  floatx4 accg[(EPI == 2) ? 4 : 1][4];
#pragma unroll
  for (int i = 0; i < 4; i++)
#pragma unroll
    for (int j = 0; j < 4; j++) {
      acc[i][j] = (floatx4){0.f, 0.f, 0.f, 0.f};
      if constexpr (EPI == 2) accg[i][j] = (floatx4){0.f, 0.f, 0.f, 0.f};
    }

  // staging: wave w, round r covers rows [w*16 + r*64, +16); lane l sources
  // row +(l>>2), col (l&3)*8 -> HW writes linearly base+l*16B.
  int srow = wave * 16 + (lane >> 2);
  int scol = (lane & 3) * 8;
  const __bf16* aSrc = act + ((size_t)(b * Tt + t0 + srow)) * K + scol;
  const __bf16* bSrc = W + (size_t)(n0 + srow) * K + scol;
  const __bf16* gSrc = W + (size_t)(NOUT + n0 + srow) * K + scol;  // EPI2 only

  auto stage = [&](int buf, int k0) {
#pragma unroll
    for (int r = 0; r < 2; r++) {
      gl_lds16(aSrc + k0 + (size_t)(64 * r) * K, &As[buf][wave * 16 + r * 64][0]);
      gl_lds16(bSrc + k0 + (size_t)(64 * r) * K, &Bs[buf][wave * 16 + r * 64][0]);
      if constexpr (EPI == 2)
        gl_lds16(gSrc + k0 + (size_t)(64 * r) * K, &Bs2[buf][wave * 16 + r * 64][0]);
    }
  };

  stage(0, 0);
  __syncthreads();          // drain prologue loads
  int cur = 0;
  for (int k0 = 0; k0 < K; k0 += 32) {
    if (k0 + 32 < K) stage(cur ^ 1, k0 + 32);   // issue next tile FIRST
    bf16x8 af[4], bfr[4], gfr[(EPI == 2) ? 4 : 1];
#pragma unroll
    for (int i = 0; i < 4; i++)
      af[i] = *(const bf16x8*)&As[cur][wm * 64 + i * 16 + l16][quad * 8];
#pragma unroll
    for (int j = 0; j < 4; j++) {
      bfr[j] = *(const bf16x8*)&Bs[cur][wn * 64 + j * 16 + l16][quad * 8];
      if constexpr (EPI == 2)
        gfr[j] = *(const bf16x8*)&Bs2[cur][wn * 64 + j * 16 + l16][quad * 8];
    }
#pragma unroll
    for (int i = 0; i < 4; i++)
#pragma unroll
      for (int j = 0; j < 4; j++) {
        acc[i][j] = __builtin_amdgcn_mfma_f32_16x16x32_bf16(af[i], bfr[j], acc[i][j], 0, 0, 0);
        if constexpr (EPI == 2)
          accg[i][j] = __builtin_amdgcn_mfma_f32_16x16x32_bf16(af[i], gfr[j], accg[i][j], 0, 0, 0);
      }
    __syncthreads();        // reads of cur done; prefetch of cur^1 landed
    cur ^= 1;
  }

  // epilogue: D row = t (i*16 + quad*4 + r), col = n (j*16 + l16)
#pragma unroll
  for (int i = 0; i < 4; i++) {
    int tb = t0 + wm * 64 + i * 16 + quad * 4;
    float mv[4];
    if constexpr (EPI == 1) {
#pragma unroll
      for (int r = 0; r < 4; r++) mv[r] = mask[(size_t)b * Tt + tb + r];
    }
#pragma unroll
    for (int j = 0; j < 4; j++) {
      int n = n0 + wn * 64 + j * 16 + l16;
      float bn = bias[n];
      float bg = (EPI == 2) ? bias[NOUT + n] : 0.f;
#pragma unroll
      for (int r = 0; r < 4; r++) {
        size_t o = ((size_t)(b * Tt + tb + r)) * NOUT + n;
        if constexpr (EPI == 0) {
          outb[o] = bfbits(acc[i][j][r] + bn);
        } else if constexpr (EPI == 1) {
          float v = fmaxf(acc[i][j][r] + bn, 0.f) * mv[r];
          outb[o] = bfbits(v);
        } else {
          float a = acc[i][j][r] + bn;
          float g = accg[i][j][r] + bg;
          outb[o] = bfbits(a / (1.f + expf(-g)));
        }
      }
    }
  }
}

// ---------------- LayerNorm over C: out = LN(in1*f1 + bf16(in2)*f2) ----------------
__global__ __launch_bounds__(256) void ln_t(
    const float* __restrict__ in1, const unsigned short* __restrict__ in2b,
    const float* __restrict__ mask, const float* __restrict__ gamma,
    const float* __restrict__ beta, float* __restrict__ out,
    unsigned short* __restrict__ outb, int m1, int m2) {
  int row = blockIdx.x * 4 + (threadIdx.x >> 6);  // b*Tt + t
  int lane = threadIdx.x & 63;
  float mv = mask[row];
  float f1 = m1 ? mv : 1.f;
  float f2 = m2 ? mv : 1.f;
  size_t base = (size_t)row * Hc;
  float v[6], sum = 0.f, sq = 0.f;
#pragma unroll
  for (int j = 0; j < 6; j++) {
    int idx = lane + 64 * j;
    float a = in1[base + idx] * f1 + bf2f(in2b[base + idx]) * f2;
    v[j] = a; sum += a; sq = fmaf(a, a, sq);
  }
#pragma unroll
  for (int off = 32; off >= 1; off >>= 1) {
    sum += __shfl_xor(sum, off, 64);
    sq  += __shfl_xor(sq,  off, 64);
  }
  float m = sum * (1.f / Hc);
  float var = sq * (1.f / Hc) - m * m;
  float rs = rsqrtf(var + 1e-4f);
#pragma unroll
  for (int j = 0; j < 6; j++) {
    int idx = lane + 64 * j;
    float o = (v[j] - m) * rs * gamma[idx] + beta[idx];
    out[base + idx] = o;
    if (outb) outb[base + idx] = bfbits(o * mv);
  }
}

// ---------------- diagnostic ----------------
__global__ void diag_kernel(float* out, float v) {
  if (blockIdx.x == 0 && threadIdx.x == 0) out[0] = v;
}

extern "C" void kernel_launch(void* const* d_in, const int* in_sizes, int n_in,
                              void* d_out, int out_size, void* d_ws, size_t ws_size,
                              hipStream_t stream) {
  const float* x_in  = (const float*)d_in[0];
  const float* xmask = (const float*)d_in[1];
  const float* log_dt = (const float*)d_in[2];
  const float* A_re = (const float*)d_in[3];
  const float* A_im = (const float*)d_in[4];
  const float* C_re = (const float*)d_in[5];
  const float* C_im = (const float*)d_in[6];
  const float* Dv   = (const float*)d_in[7];
  const float* Wout = (const float*)d_in[8];
  const float* bout = (const float*)d_in[9];
  const float* g1   = (const float*)d_in[10];
  const float* be1  = (const float*)d_in[11];
  const float* W1   = (const float*)d_in[12];
  const float* bf1  = (const float*)d_in[13];
  const float* W2   = (const float*)d_in[14];
  const float* bf2  = (const float*)d_in[15];
  const float* g2   = (const float*)d_in[16];
  const float* be2  = (const float*)d_in[17];

  const size_t NXf   = (size_t)Bq * Hc * Tt;          // 12,582,912 floats
  const size_t NP    = (size_t)LYR * Hc * N2;         // 73,728
  const size_t YBFf  = NXf / 2;                       // bf16 y / x1b region, in floats
  const size_t HBFf  = (size_t)Bq * Tt * HFq / 2;     // bf16 h region, in floats
  const size_t WOUTf = (size_t)LYR * TWOH * Hc / 2;
  const size_t W1f   = (size_t)LYR * HFq * Hc / 2;
  const size_t W2f   = (size_t)LYR * Hc * HFq / 2;

  size_t need = 2 * NXf + YBFf + HBFf + WOUTf + W1f + W2f + 6 * NP;
  if (ws_size / 4 < need) {
    diag_kernel<<<1, 64, 0, stream>>>((float*)d_out, 1000.0f + (float)(ws_size >> 20));
    return;
  }

  float* ws = (float*)d_ws;
  float* xT   = ws;                       // (B,T,C) fp32 layer state
  float* tmp  = xT + NXf;                 // first half: U fp16 overlay; second half: tmpb bf16
  float* ybfF = tmp + NXf;                // bf16 (B,T,C): y, then x1*mask
  float* hbfF = ybfF + YBFf;              // bf16 (B,T,HF): ffn hidden; scan overlays
  float* wobF = hbfF + HBFf;              // bf16 weights
  float* w1bF = wobF + WOUTf;
  float* w2bF = w1bF + W1f;
  float* wre  = w2bF + W2f;
  float* wim  = wre + NP;
  float* cdre = wim + NP;
  float* cdim = cdre + NP;
  float* wSre = cdim + NP;
  float* wSim = wSre + NP;

  unsigned short* ybf = (unsigned short*)ybfF;
  unsigned short* hbf = (unsigned short*)hbfF;
  unsigned short* wob = (unsigned short*)wobF;
  unsigned short* w1b = (unsigned short*)w1bF;
  unsigned short* w2b = (unsigned short*)w2bF;
  float* x1 = (float*)d_out;              // (B,T,C) fp32 post-LN1 lives in d_out

  // scan overlays: U in tmp first half; tmpb bf16 in second half (disjoint);
  // St/Yb/mats in hbf region (dead until FFN)
  f16_t* Ub   = (f16_t*)tmp;                                  // 12.58M fp16 = 6.29M fl
  unsigned short* tmpb = (unsigned short*)(tmp + NXf / 2);    // 12.58M bf16
  f16_t* St16 = (f16_t*)hbfF;                                 // 12.58M fp16
  unsigned short* Ybi = (unsigned short*)(hbfF + YBFf);       // 12.58M bf16
  f16_t* Ag   = (f16_t*)(hbfF + 2 * YBFf);                    // 384*8192 fp16
  f16_t* Wg   = Ag + (size_t)384 * 8192;                      // 384*4096 fp16

  param_kernel<<<(LYR * Hc * N2 + 255) / 256, 256, 0, stream>>>(
      log_dt, A_re, A_im, C_re, C_im, wre, wim, cdre, cdim, wSre, wSim);
  cvt_bf16_kernel<<<(int)(2 * WOUTf + 1023) / 1024, 256, 0, stream>>>(Wout, wob, (int)(WOUTf / 2));
  cvt_bf16_kernel<<<(int)(2 * W1f + 1023) / 1024, 256, 0, stream>>>(W1, w1b, (int)(W1f / 2));
  cvt_bf16_kernel<<<(int)(2 * W2f + 1023) / 1024, 256, 0, stream>>>(W2, w2b, (int)(W2f / 2));
  transpose_fwd<<<dim3(Tt / 32, Hc / 32, Bq), dim3(32, 8), 0, stream>>>(x_in, xT);

  for (int i = 0; i < LYR; i++) {
    size_t po = (size_t)i * Hc * N2;

    // --- S4D scan via MFMA (chunked Toeplitz + carry) ---
    pack_u<<<dim3(Tt / 64, Hc / 64, Bq), 256, 0, stream>>>(xT, xmask, Ub);
    build_mats<<<Hc, 256, 0, stream>>>(wre + po, wim + po, cdre + po, cdim + po, Ag, Wg);
    gemm_state<<<dim3(NJ / 128, Hc), 256, 0, stream>>>(Ub, Wg, St16);
    scan_prefix2<<<(Hc * Bq * N2) / 256, 256, 0, stream>>>(St16, wSre + po, wSim + po);
    gemm_out<<<dim3(NJ / 128, Hc), 256, 0, stream>>>(Ub, Ag, St16, Dv + (size_t)i * Hc, Ybi);
    unpack_y<<<dim3(Tt / 64, Hc / 64, Bq), 256, 0, stream>>>(Ybi, ybf);

    // glu = bf16(GLU(Wout*y + bout)) -> tmpb
    mfma_gemm<2><<<dim3(Tt / 128, Hc / 128, Bq), 256, 0, stream>>>(
        (const __bf16*)ybf, (const __bf16*)(wob + (size_t)i * TWOH * Hc),
        bout + (size_t)i * TWOH, xmask, tmpb, Hc, Hc);

    // x1 = LN(x*mask + glu) -> d_out fp32 ; x1b = bf16(x1*mask) -> ybf
    ln_t<<<(Bq * Tt) / 4, 256, 0, stream>>>(
        xT, tmpb, xmask, g1 + (size_t)i * Hc, be1 + (size_t)i * Hc, x1, ybf, 1, 0);

    // h = bf16(relu(W1*x1b + bf1) * mask) -> hbf
    mfma_gemm<1><<<dim3(Tt / 128, HFq / 128, Bq), 256, 0, stream>>>(
        (const __bf16*)ybf, (const __bf16*)(w1b + (size_t)i * HFq * Hc),
        bf1 + (size_t)i * HFq, xmask, hbf, Hc, HFq);

    // f = bf16(W2*h + bf2) -> tmpb
    mfma_gemm<0><<<dim3(Tt / 128, Hc / 128, Bq), 256, 0, stream>>>(
        (const __bf16*)hbf, (const __bf16*)(w2b + (size_t)i * Hc * HFq),
        bf2 + (size_t)i * Hc, xmask, tmpb, HFq, Hc);

    // x = LN(x1 + f*mask) -> xT
    ln_t<<<(Bq * Tt) / 4, 256, 0, stream>>>(
        x1, tmpb, xmask, g2 + (size_t)i * Hc, be2 + (size_t)i * Hc, xT, nullptr, 0, 1);
  }

  transpose_bwd<<<dim3(Tt / 32, Hc / 32, Bq), dim3(32, 8), 0, stream>>>(xT, xmask, (float*)d_out);
}

// Round 9
// 1843.438 us; speedup vs baseline: 1.1610x; 1.0310x over previous
//
#include <hip/hip_runtime.h>
#include <math.h>

#define Bq 16
#define Hc 384
#define Tt 2048
#define N2 32
#define LYR 6
#define HFq 1536
#define TWOH 768
#define CHUNK 64
#define NCH (Tt/CHUNK)   // 32
#define NJ (Bq*NCH)      // 512 chunk-columns per head
#define UH (NJ*CHUNK)    // 32768 elements per head in U/St/Y layouts

typedef __bf16 bf16x8 __attribute__((ext_vector_type(8)));
typedef float floatx4 __attribute__((ext_vector_type(4)));
typedef _Float16 f16_t;
typedef f16_t fp16x8 __attribute__((ext_vector_type(8)));
typedef f16_t fp16x4 __attribute__((ext_vector_type(4)));

__device__ __forceinline__ unsigned short bfbits(float f) {
  union { float f; unsigned u; } x; x.f = f;
  return (unsigned short)((x.u + 0x7FFF + ((x.u >> 16) & 1)) >> 16);
}
__device__ __forceinline__ float bf2f(unsigned short u) {
  union { unsigned u; float f; } x; x.u = ((unsigned)u) << 16; return x.f;
}

// async global->LDS, 16B per lane; dest is wave-uniform base, HW writes lane i
// at base + i*16B (linear). Source address is per-lane.
__device__ __forceinline__ void gl_lds16(const void* g, void* l) {
  __builtin_amdgcn_global_load_lds(
      (const __attribute__((address_space(1))) void*)g,
      (__attribute__((address_space(3))) void*)l, 16, 0, 0);
}

// ---------------- param precompute (fp64 for accuracy) ----------------
__global__ void param_kernel(const float* __restrict__ log_dt,
                             const float* __restrict__ A_re, const float* __restrict__ A_im,
                             const float* __restrict__ C_re, const float* __restrict__ C_im,
                             float* __restrict__ wre, float* __restrict__ wim,
                             float* __restrict__ cdre, float* __restrict__ cdim,
                             float* __restrict__ wSre, float* __restrict__ wSim) {
  int idx = blockIdx.x * blockDim.x + threadIdx.x;
  if (idx >= LYR * Hc * N2) return;
  int hn = idx / N2;
  double dt = exp((double)log_dt[hn]);
  double are = (double)A_re[idx], aim = (double)A_im[idx];
  double dre = are * dt, dimv = aim * dt;
  double er = exp(dre);
  double wr = er * cos(dimv), wi_ = er * sin(dimv);
  double den = are * are + aim * aim;
  double nr = wr - 1.0, ni = wi_;
  double qr = (nr * are + ni * aim) / den;
  double qi = (ni * are - nr * aim) / den;
  double cr = (double)C_re[idx], ci = (double)C_im[idx];
  cdre[idx] = (float)(2.0 * (cr * qr - ci * qi));
  cdim[idx] = (float)(2.0 * (cr * qi + ci * qr));
  wre[idx] = (float)wr; wim[idx] = (float)wi_;
  double es = exp(dre * (double)CHUNK);
  wSre[idx] = (float)(es * cos(dimv * (double)CHUNK));
  wSim[idx] = (float)(es * sin(dimv * (double)CHUNK));
}

// ---------------- weight fp32 -> bf16 (RNE) ----------------
__global__ void cvt_bf16_kernel(const float* __restrict__ in, unsigned short* __restrict__ out,
                                int n4) {
  int idx = blockIdx.x * 256 + threadIdx.x;
  if (idx >= n4) return;
  float4 v = ((const float4*)in)[idx];
  ushort4 o;
  o.x = bfbits(v.x); o.y = bfbits(v.y); o.z = bfbits(v.z); o.w = bfbits(v.w);
  ((ushort4*)out)[idx] = o;
}

// ---------------- transpose (B,C,T) -> (B,T,C) ----------------
__global__ __launch_bounds__(256) void transpose_fwd(const float* __restrict__ in,
                                                     float* __restrict__ out) {
  __shared__ float tile[32][33];
  int tx = threadIdx.x, ty = threadIdx.y;
  int t0 = blockIdx.x * 32, c0 = blockIdx.y * 32, b = blockIdx.z;
#pragma unroll
  for (int k = 0; k < 4; k++)
    tile[ty + 8 * k][tx] = in[((size_t)(b * Hc + c0 + ty + 8 * k)) * Tt + t0 + tx];
  __syncthreads();
#pragma unroll
  for (int k = 0; k < 4; k++)
    out[((size_t)(b * Tt + t0 + ty + 8 * k)) * Hc + c0 + tx] = tile[tx][ty + 8 * k];
}

// ---------------- transpose (B,T,C) -> (B,C,T) with mask ----------------
__global__ __launch_bounds__(256) void transpose_bwd(const float* __restrict__ in,
                                                     const float* __restrict__ mask,
                                                     float* __restrict__ out) {
  __shared__ float tile[32][33];
  int tx = threadIdx.x, ty = threadIdx.y;
  int t0 = blockIdx.x * 32, c0 = blockIdx.y * 32, b = blockIdx.z;
#pragma unroll
  for (int k = 0; k < 4; k++)
    tile[ty + 8 * k][tx] = in[((size_t)(b * Tt + t0 + ty + 8 * k)) * Hc + c0 + tx];
  __syncthreads();
  float mv = mask[(size_t)b * Tt + t0 + tx];
#pragma unroll
  for (int k = 0; k < 4; k++)
    out[((size_t)(b * Hc + c0 + ty + 8 * k)) * Tt + t0 + tx] = tile[tx][ty + 8 * k] * mv;
}

// ---------------- pack: xT (B,T,C) fp32 * mask -> U[h][j][tau] fp16 ----------------
__global__ __launch_bounds__(256) void pack_u(const float* __restrict__ xT,
                                              const float* __restrict__ mask,
                                              f16_t* __restrict__ U) {
  __shared__ float tile[64][65];
  int tid = threadIdx.x;
  int t0 = blockIdx.x * 64, h0 = blockIdx.y * 64, b = blockIdx.z;
#pragma unroll
  for (int p = 0; p < 4; p++) {
    int idx = p * 256 + tid;
    int row = idx >> 4, c4 = (idx & 15) * 4;
    float4 v = *(const float4*)&xT[((size_t)(b * Tt + t0 + row)) * Hc + h0 + c4];
    float mv = mask[(size_t)b * Tt + t0 + row];
    tile[row][c4] = v.x * mv; tile[row][c4 + 1] = v.y * mv;
    tile[row][c4 + 2] = v.z * mv; tile[row][c4 + 3] = v.w * mv;
  }
  __syncthreads();
#pragma unroll
  for (int p = 0; p < 2; p++) {
    int idx = p * 256 + tid;
    int hr = idx >> 3, g = (idx & 7) * 8;
    fp16x8 o;
#pragma unroll
    for (int i = 0; i < 8; i++) o[i] = (f16_t)tile[g + i][hr];
    *(fp16x8*)&U[(size_t)(h0 + hr) * UH + (size_t)b * Tt + t0 + g] = o;
  }
}

// ---------------- build per-head matrices: Ag = [T | V] (64x128), Wg (64x64) ----------------
__global__ __launch_bounds__(256) void build_mats(
    const float* __restrict__ wre, const float* __restrict__ wim,
    const float* __restrict__ cdre, const float* __restrict__ cdim,
    f16_t* __restrict__ Ag, f16_t* __restrict__ Wg) {
  __shared__ float pre[65][32], pim[65][32], Kc[64], cdr_s[32], cdi_s[32];
  int h = blockIdx.x, tid = threadIdx.x;
  if (tid < 32) {
    float wr = wre[h * N2 + tid], wi = wim[h * N2 + tid];
    cdr_s[tid] = cdre[h * N2 + tid];
    cdi_s[tid] = cdim[h * N2 + tid];
    float pr = 1.f, pi = 0.f;
    for (int p = 0; p <= 64; p++) {
      pre[p][tid] = pr; pim[p][tid] = pi;
      float nr2 = pr * wr - pi * wi;
      pi = pr * wi + pi * wr;
      pr = nr2;
    }
  }
  __syncthreads();
  if (tid < 64) {
    float s = 0.f;
    for (int n = 0; n < 32; n++)
      s = fmaf(cdr_s[n], pre[tid][n], fmaf(-cdi_s[n], pim[tid][n], s));
    Kc[tid] = s;
  }
  __syncthreads();
  for (int i = tid; i < 64 * 128; i += 256) {
    int m = i >> 7, k = i & 127;
    float v;
    if (k < 64) {
      v = (m >= k) ? Kc[m - k] : 0.f;
    } else {
      int kk = k - 64, n = kk >> 1;
      v = (kk & 1) ? -fmaf(cdr_s[n], pim[m + 1][n], cdi_s[n] * pre[m + 1][n])
                   :  fmaf(cdr_s[n], pre[m + 1][n], -cdi_s[n] * pim[m + 1][n]);
    }
    Ag[(size_t)h * 8192 + i] = (f16_t)v;
  }
  for (int i = tid; i < 64 * 64; i += 256) {
    int m = i >> 6, tau = i & 63, n = m >> 1;
    float v = (m & 1) ? pim[63 - tau][n] : pre[63 - tau][n];
    Wg[(size_t)h * 4096 + i] = (f16_t)v;
  }
}

// ---------------- state GEMM: S_end[m'][j] = Wg . U  (per head), fp16 out ----------------
__global__ __launch_bounds__(256) void gemm_state(const f16_t* __restrict__ U,
                                                  const f16_t* __restrict__ Wg,
                                                  f16_t* __restrict__ St) {
  __shared__ f16_t Aw[64][72];
  __shared__ f16_t Bu[128][72];
  int tid = threadIdx.x;
  int j0 = blockIdx.x * 128, h = blockIdx.y;
#pragma unroll
  for (int p = 0; p < 2; p++) {
    int idx = p * 256 + tid;
    int row = idx >> 3, c8 = (idx & 7) * 8;
    *(fp16x8*)&Aw[row][c8] = *(const fp16x8*)&Wg[(size_t)h * 4096 + row * 64 + c8];
  }
#pragma unroll
  for (int p = 0; p < 4; p++) {
    int idx = p * 256 + tid;
    int row = idx >> 3, c8 = (idx & 7) * 8;
    *(fp16x8*)&Bu[row][c8] =
        *(const fp16x8*)&U[(size_t)h * UH + (size_t)(j0 + row) * CHUNK + c8];
  }
  __syncthreads();
  int wave = tid >> 6, lane = tid & 63, l16 = lane & 15, quad = lane >> 4;
  int m0 = wave * 16;
  floatx4 acc[8];
#pragma unroll
  for (int jt = 0; jt < 8; jt++) acc[jt] = (floatx4){0.f, 0.f, 0.f, 0.f};
#pragma unroll
  for (int kk = 0; kk < 2; kk++) {
    fp16x8 a = *(const fp16x8*)&Aw[m0 + l16][kk * 32 + quad * 8];
#pragma unroll
    for (int jt = 0; jt < 8; jt++) {
      fp16x8 bb = *(const fp16x8*)&Bu[jt * 16 + l16][kk * 32 + quad * 8];
      acc[jt] = __builtin_amdgcn_mfma_f32_16x16x32_f16(a, bb, acc[jt], 0, 0, 0);
    }
  }
#pragma unroll
  for (int jt = 0; jt < 8; jt++) {
    int j = j0 + jt * 16 + l16;
    fp16x4 o;
#pragma unroll
    for (int r = 0; r < 4; r++) o[r] = (f16_t)acc[jt][r];
    *(fp16x4*)&St[(size_t)h * UH + (size_t)j * CHUNK + m0 + quad * 4] = o;
  }
}

// ---------------- prefix over chunks: local end-states -> carry-in states ----------------
__global__ __launch_bounds__(256) void scan_prefix2(
    f16_t* __restrict__ St,
    const float* __restrict__ wSre, const float* __restrict__ wSim) {
  int gid = blockIdx.x * 256 + threadIdx.x;  // (h*16 + b)*32 + n
  if (gid >= Hc * Bq * N2) return;
  int n = gid & 31;
  int b = (gid >> 5) & 15;
  int h = gid >> 9;
  float wr = wSre[h * N2 + n], wi = wSim[h * N2 + n];
  float cr = 0.f, ci = 0.f;
  unsigned* base = (unsigned*)(St + (size_t)h * UH + (size_t)b * Tt + 2 * n);
  for (int c = 0; c < NCH; c++) {
    union { unsigned u; f16_t h2[2]; } in, out;
    in.u = base[c * 32];
    float sre = (float)in.h2[0], sim = (float)in.h2[1];
    out.h2[0] = (f16_t)cr; out.h2[1] = (f16_t)ci;
    base[c * 32] = out.u;
    float c0 = cr;
    cr = fmaf(wr, c0, fmaf(-wi, ci, sre));
    ci = fmaf(wr, ci, fmaf(wi, c0, sim));
  }
}

// ---------------- out GEMM: Y = gelu([T|V].[U;S0] + D*u), bf16 out [h][j][tau] ----------------
__global__ __launch_bounds__(256) void gemm_out(
    const f16_t* __restrict__ U, const f16_t* __restrict__ Ag,
    const f16_t* __restrict__ St, const float* __restrict__ Dv,
    unsigned short* __restrict__ Yb) {
  __shared__ f16_t Aa[64][136];
  __shared__ f16_t Bb[128][136];
  int tid = threadIdx.x;
  int j0 = blockIdx.x * 128, h = blockIdx.y;
#pragma unroll
  for (int p = 0; p < 4; p++) {
    int idx = p * 256 + tid;
    int row = idx >> 4, c8 = (idx & 15) * 8;
    *(fp16x8*)&Aa[row][c8] = *(const fp16x8*)&Ag[(size_t)h * 8192 + row * 128 + c8];
  }
#pragma unroll
  for (int p = 0; p < 4; p++) {
    int idx = p * 256 + tid;
    int row = idx >> 3, c8 = (idx & 7) * 8;
    *(fp16x8*)&Bb[row][c8] =
        *(const fp16x8*)&U[(size_t)h * UH + (size_t)(j0 + row) * CHUNK + c8];
    *(fp16x8*)&Bb[row][64 + c8] =
        *(const fp16x8*)&St[(size_t)h * UH + (size_t)(j0 + row) * CHUNK + c8];
  }
  __syncthreads();
  int wave = tid >> 6, lane = tid & 63, l16 = lane & 15, quad = lane >> 4;
  int m0 = wave * 16;
  floatx4 acc[8];
#pragma unroll
  for (int jt = 0; jt < 8; jt++) acc[jt] = (floatx4){0.f, 0.f, 0.f, 0.f};
#pragma unroll
  for (int kk = 0; kk < 4; kk++) {
    fp16x8 a = *(const fp16x8*)&Aa[m0 + l16][kk * 32 + quad * 8];
#pragma unroll
    for (int jt = 0; jt < 8; jt++) {
      fp16x8 bb = *(const fp16x8*)&Bb[jt * 16 + l16][kk * 32 + quad * 8];
      acc[jt] = __builtin_amdgcn_mfma_f32_16x16x32_f16(a, bb, acc[jt], 0, 0, 0);
    }
  }
  float d = Dv[h];
  int tb = m0 + quad * 4;
#pragma unroll
  for (int jt = 0; jt < 8; jt++) {
    int jr = jt * 16 + l16;
    fp16x4 u4 = *(const fp16x4*)&Bb[jr][tb];
    ushort4 o;
#pragma unroll
    for (int r = 0; r < 4; r++) {
      float v = fmaf(d, (float)u4[r], acc[jt][r]);
      v = 0.5f * v * (1.0f + erff(v * 0.70710678118654752f));
      ((unsigned short*)&o)[r] = bfbits(v);
    }
    *(ushort4*)&Yb[(size_t)h * UH + (size_t)(j0 + jr) * CHUNK + tb] = o;
  }
}

// ---------------- unpack: Yb[h][j][tau] bf16 -> ybf (B,T,C) bf16 ----------------
__global__ __launch_bounds__(256) void unpack_y(const unsigned short* __restrict__ Yb,
                                                unsigned short* __restrict__ yb) {
  __shared__ unsigned short tile[64][65];
  int tid = threadIdx.x;
  int t0 = blockIdx.x * 64, h0 = blockIdx.y * 64, b = blockIdx.z;
#pragma unroll
  for (int p = 0; p < 2; p++) {
    int idx = p * 256 + tid;
    int hr = idx >> 3, g = (idx & 7) * 8;
    uint4 v = *(const uint4*)&Yb[(size_t)(h0 + hr) * UH + (size_t)b * Tt + t0 + g];
    const unsigned short* s = (const unsigned short*)&v;
#pragma unroll
    for (int i = 0; i < 8; i++) tile[hr][g + i] = s[i];
  }
  __syncthreads();
#pragma unroll
  for (int p = 0; p < 2; p++) {
    int idx = p * 256 + tid;
    int tr = idx >> 3, g = (idx & 7) * 8;
    unsigned short o[8];
#pragma unroll
    for (int i = 0; i < 8; i++) o[i] = tile[g + i][tr];
    *(uint4*)&yb[((size_t)(b * Tt + t0 + tr)) * Hc + h0 + g] = *(uint4*)o;
  }
}

// ---------------- MFMA GEMM: out(B,T,N) = act(B,T,K) x W(N,K)^T, bf16 out ----------------
// T3+T4: 3-buffer LDS ring, counted s_waitcnt vmcnt(N) + raw s_barrier (one per
// k-step), 2 k-tiles in flight. T2: bank-conflict-free via pre-swizzled global
// source (LDS dest stays linear for global_load_lds) + matching XOR on ds_read:
//   stored chunk c of row r holds source chunk c ^ ((r>>1)&3).
// EPI 0: outb = bf16(acc + bias)
// EPI 1: outb = bf16(relu(acc + bias) * mask)
// EPI 2: GLU, W has 2N rows: outb = bf16((a+ba)*sigmoid(g+bg))
template <int EPI>
__global__ __launch_bounds__(256) void mfma_gemm(
    const __bf16* __restrict__ act, const __bf16* __restrict__ W,
    const float* __restrict__ bias, const float* __restrict__ mask,
    unsigned short* __restrict__ outb, int K, int NOUT) {
  __shared__ __bf16 As[3][128][32];
  __shared__ __bf16 Bs[3][128][32];
  __shared__ __bf16 Bs2[(EPI == 2) ? 3 : 1][(EPI == 2) ? 128 : 1][32];
  int tid = threadIdx.x;
  int b = blockIdx.z;
  int t0 = blockIdx.x * 128, n0 = blockIdx.y * 128;
  int wave = tid >> 6, lane = tid & 63, l16 = lane & 15, quad = lane >> 4;
  int wm = wave >> 1, wn = wave & 1;

  floatx4 acc[4][4];
  floatx4 accg[(EPI == 2) ? 4 : 1][4];
#pragma unroll
  for (int i = 0; i < 4; i++)
#pragma unroll
    for (int j = 0; j < 4; j++) {
      acc[i][j] = (floatx4){0.f, 0.f, 0.f, 0.f};
      if constexpr (EPI == 2) accg[i][j] = (floatx4){0.f, 0.f, 0.f, 0.f};
    }

  // staging: wave w, round r covers rows [w*16 + r*64, +16); lane l sources
  // row +(l>>2); source chunk pre-swizzled: c' = (l&3) ^ ((l>>3)&3) so that
  // LDS slot c of row r holds source chunk c ^ ((r>>1)&3).
  int srow = wave * 16 + (lane >> 2);
  int scol = (((lane & 3) ^ ((lane >> 3) & 3)) * 8);
  const __bf16* aSrc = act + ((size_t)(b * Tt + t0 + srow)) * K + scol;
  const __bf16* bSrc = W + (size_t)(n0 + srow) * K + scol;
  const __bf16* gSrc = W + (size_t)(NOUT + n0 + srow) * K + scol;  // EPI2 only

  auto stage = [&](int buf, int k0) {
#pragma unroll
    for (int r = 0; r < 2; r++) {
      gl_lds16(aSrc + k0 + (size_t)(64 * r) * K, &As[buf][wave * 16 + r * 64][0]);
      gl_lds16(bSrc + k0 + (size_t)(64 * r) * K, &Bs[buf][wave * 16 + r * 64][0]);
      if constexpr (EPI == 2)
        gl_lds16(gSrc + k0 + (size_t)(64 * r) * K, &Bs2[buf][wave * 16 + r * 64][0]);
    }
  };

  const int NT = K >> 5;           // k-tiles of 32
  int swz = (quad ^ ((l16 >> 1) & 3)) << 4;   // byte offset of swizzled 16B chunk
  stage(0, 0);
  stage(1, 32);                    // NT >= 12 always here
  for (int t = 0; t < NT; ++t) {
    // wait for tile t's own loads (oldest); keep tile t+1's in flight.
    if (t + 1 < NT) {
      asm volatile("s_waitcnt vmcnt(%0)" :: "i"((EPI == 2) ? 6 : 4) : "memory");
    } else {
      asm volatile("s_waitcnt vmcnt(0)" ::: "memory");
    }
    __builtin_amdgcn_s_barrier();
    __builtin_amdgcn_sched_barrier(0);
    int cur = t % 3;
    bf16x8 af[4], bfr[4], gfr[(EPI == 2) ? 4 : 1];
#pragma unroll
    for (int i = 0; i < 4; i++)
      af[i] = *(const bf16x8*)((const char*)&As[cur][0][0] +
                               (wm * 64 + i * 16 + l16) * 64 + swz);
#pragma unroll
    for (int j = 0; j < 4; j++) {
      bfr[j] = *(const bf16x8*)((const char*)&Bs[cur][0][0] +
                                (wn * 64 + j * 16 + l16) * 64 + swz);
      if constexpr (EPI == 2)
        gfr[j] = *(const bf16x8*)((const char*)&Bs2[cur][0][0] +
                                  (wn * 64 + j * 16 + l16) * 64 + swz);
    }
    if (t + 2 < NT) stage((t + 2) % 3, (t + 2) * 32);
#pragma unroll
    for (int i = 0; i < 4; i++)
#pragma unroll
      for (int j = 0; j < 4; j++) {
        acc[i][j] = __builtin_amdgcn_mfma_f32_16x16x32_bf16(af[i], bfr[j], acc[i][j], 0, 0, 0);
        if constexpr (EPI == 2)
          accg[i][j] = __builtin_amdgcn_mfma_f32_16x16x32_bf16(af[i], gfr[j], accg[i][j], 0, 0, 0);
      }
  }

  // epilogue: D row = t (i*16 + quad*4 + r), col = n (j*16 + l16)
#pragma unroll
  for (int i = 0; i < 4; i++) {
    int tb = t0 + wm * 64 + i * 16 + quad * 4;
    float mv[4];
    if constexpr (EPI == 1) {
#pragma unroll
      for (int r = 0; r < 4; r++) mv[r] = mask[(size_t)b * Tt + tb + r];
    }
#pragma unroll
    for (int j = 0; j < 4; j++) {
      int n = n0 + wn * 64 + j * 16 + l16;
      float bn = bias[n];
      float bg = (EPI == 2) ? bias[NOUT + n] : 0.f;
#pragma unroll
      for (int r = 0; r < 4; r++) {
        size_t o = ((size_t)(b * Tt + tb + r)) * NOUT + n;
        if constexpr (EPI == 0) {
          outb[o] = bfbits(acc[i][j][r] + bn);
        } else if constexpr (EPI == 1) {
          float v = fmaxf(acc[i][j][r] + bn, 0.f) * mv[r];
          outb[o] = bfbits(v);
        } else {
          float a = acc[i][j][r] + bn;
          float g = accg[i][j][r] + bg;
          outb[o] = bfbits(a / (1.f + expf(-g)));
        }
      }
    }
  }
}

// ---------------- LayerNorm over C: out = LN(in1*f1 + bf16(in2)*f2) ----------------
__global__ __launch_bounds__(256) void ln_t(
    const float* __restrict__ in1, const unsigned short* __restrict__ in2b,
    const float* __restrict__ mask, const float* __restrict__ gamma,
    const float* __restrict__ beta, float* __restrict__ out,
    unsigned short* __restrict__ outb, int m1, int m2) {
  int row = blockIdx.x * 4 + (threadIdx.x >> 6);  // b*Tt + t
  int lane = threadIdx.x & 63;
  float mv = mask[row];
  float f1 = m1 ? mv : 1.f;
  float f2 = m2 ? mv : 1.f;
  size_t base = (size_t)row * Hc;
  float v[6], sum = 0.f, sq = 0.f;
#pragma unroll
  for (int j = 0; j < 6; j++) {
    int idx = lane + 64 * j;
    float a = in1[base + idx] * f1 + bf2f(in2b[base + idx]) * f2;
    v[j] = a; sum += a; sq = fmaf(a, a, sq);
  }
#pragma unroll
  for (int off = 32; off >= 1; off >>= 1) {
    sum += __shfl_xor(sum, off, 64);
    sq  += __shfl_xor(sq,  off, 64);
  }
  float m = sum * (1.f / Hc);
  float var = sq * (1.f / Hc) - m * m;
  float rs = rsqrtf(var + 1e-4f);
#pragma unroll
  for (int j = 0; j < 6; j++) {
    int idx = lane + 64 * j;
    float o = (v[j] - m) * rs * gamma[idx] + beta[idx];
    out[base + idx] = o;
    if (outb) outb[base + idx] = bfbits(o * mv);
  }
}

// ---------------- diagnostic ----------------
__global__ void diag_kernel(float* out, float v) {
  if (blockIdx.x == 0 && threadIdx.x == 0) out[0] = v;
}

extern "C" void kernel_launch(void* const* d_in, const int* in_sizes, int n_in,
                              void* d_out, int out_size, void* d_ws, size_t ws_size,
                              hipStream_t stream) {
  const float* x_in  = (const float*)d_in[0];
  const float* xmask = (const float*)d_in[1];
  const float* log_dt = (const float*)d_in[2];
  const float* A_re = (const float*)d_in[3];
  const float* A_im = (const float*)d_in[4];
  const float* C_re = (const float*)d_in[5];
  const float* C_im = (const float*)d_in[6];
  const float* Dv   = (const float*)d_in[7];
  const float* Wout = (const float*)d_in[8];
  const float* bout = (const float*)d_in[9];
  const float* g1   = (const float*)d_in[10];
  const float* be1  = (const float*)d_in[11];
  const float* W1   = (const float*)d_in[12];
  const float* bf1  = (const float*)d_in[13];
  const float* W2   = (const float*)d_in[14];
  const float* bf2  = (const float*)d_in[15];
  const float* g2   = (const float*)d_in[16];
  const float* be2  = (const float*)d_in[17];

  const size_t NXf   = (size_t)Bq * Hc * Tt;          // 12,582,912 floats
  const size_t NP    = (size_t)LYR * Hc * N2;         // 73,728
  const size_t YBFf  = NXf / 2;                       // bf16 y / x1b region, in floats
  const size_t HBFf  = (size_t)Bq * Tt * HFq / 2;     // bf16 h region, in floats
  const size_t WOUTf = (size_t)LYR * TWOH * Hc / 2;
  const size_t W1f   = (size_t)LYR * HFq * Hc / 2;
  const size_t W2f   = (size_t)LYR * Hc * HFq / 2;

  size_t need = 2 * NXf + YBFf + HBFf + WOUTf + W1f + W2f + 6 * NP;
  if (ws_size / 4 < need) {
    diag_kernel<<<1, 64, 0, stream>>>((float*)d_out, 1000.0f + (float)(ws_size >> 20));
    return;
  }

  float* ws = (float*)d_ws;
  float* xT   = ws;                       // (B,T,C) fp32 layer state
  float* tmp  = xT + NXf;                 // first half: U fp16 overlay; second half: tmpb bf16
  float* ybfF = tmp + NXf;                // bf16 (B,T,C): y, then x1*mask
  float* hbfF = ybfF + YBFf;              // bf16 (B,T,HF): ffn hidden; scan overlays
  float* wobF = hbfF + HBFf;              // bf16 weights
  float* w1bF = wobF + WOUTf;
  float* w2bF = w1bF + W1f;
  float* wre  = w2bF + W2f;
  float* wim  = wre + NP;
  float* cdre = wim + NP;
  float* cdim = cdre + NP;
  float* wSre = cdim + NP;
  float* wSim = wSre + NP;

  unsigned short* ybf = (unsigned short*)ybfF;
  unsigned short* hbf = (unsigned short*)hbfF;
  unsigned short* wob = (unsigned short*)wobF;
  unsigned short* w1b = (unsigned short*)w1bF;
  unsigned short* w2b = (unsigned short*)w2bF;
  float* x1 = (float*)d_out;              // (B,T,C) fp32 post-LN1 lives in d_out

  // scan overlays: U in tmp first half; tmpb bf16 in second half (disjoint);
  // St/Yb/mats in hbf region (dead until FFN)
  f16_t* Ub   = (f16_t*)tmp;                                  // 12.58M fp16 = 6.29M fl
  unsigned short* tmpb = (unsigned short*)(tmp + NXf / 2);    // 12.58M bf16
  f16_t* St16 = (f16_t*)hbfF;                                 // 12.58M fp16
  unsigned short* Ybi = (unsigned short*)(hbfF + YBFf);       // 12.58M bf16
  f16_t* Ag   = (f16_t*)(hbfF + 2 * YBFf);                    // 384*8192 fp16
  f16_t* Wg   = Ag + (size_t)384 * 8192;                      // 384*4096 fp16

  param_kernel<<<(LYR * Hc * N2 + 255) / 256, 256, 0, stream>>>(
      log_dt, A_re, A_im, C_re, C_im, wre, wim, cdre, cdim, wSre, wSim);
  cvt_bf16_kernel<<<(int)(2 * WOUTf + 1023) / 1024, 256, 0, stream>>>(Wout, wob, (int)(WOUTf / 2));
  cvt_bf16_kernel<<<(int)(2 * W1f + 1023) / 1024, 256, 0, stream>>>(W1, w1b, (int)(W1f / 2));
  cvt_bf16_kernel<<<(int)(2 * W2f + 1023) / 1024, 256, 0, stream>>>(W2, w2b, (int)(W2f / 2));
  transpose_fwd<<<dim3(Tt / 32, Hc / 32, Bq), dim3(32, 8), 0, stream>>>(x_in, xT);

  for (int i = 0; i < LYR; i++) {
    size_t po = (size_t)i * Hc * N2;

    // --- S4D scan via MFMA (chunked Toeplitz + carry) ---
    pack_u<<<dim3(Tt / 64, Hc / 64, Bq), 256, 0, stream>>>(xT, xmask, Ub);
    build_mats<<<Hc, 256, 0, stream>>>(wre + po, wim + po, cdre + po, cdim + po, Ag, Wg);
    gemm_state<<<dim3(NJ / 128, Hc), 256, 0, stream>>>(Ub, Wg, St16);
    scan_prefix2<<<(Hc * Bq * N2) / 256, 256, 0, stream>>>(St16, wSre + po, wSim + po);
    gemm_out<<<dim3(NJ / 128, Hc), 256, 0, stream>>>(Ub, Ag, St16, Dv + (size_t)i * Hc, Ybi);
    unpack_y<<<dim3(Tt / 64, Hc / 64, Bq), 256, 0, stream>>>(Ybi, ybf);

    // glu = bf16(GLU(Wout*y + bout)) -> tmpb
    mfma_gemm<2><<<dim3(Tt / 128, Hc / 128, Bq), 256, 0, stream>>>(
        (const __bf16*)ybf, (const __bf16*)(wob + (size_t)i * TWOH * Hc),
        bout + (size_t)i * TWOH, xmask, tmpb, Hc, Hc);

    // x1 = LN(x*mask + glu) -> d_out fp32 ; x1b = bf16(x1*mask) -> ybf
    ln_t<<<(Bq * Tt) / 4, 256, 0, stream>>>(
        xT, tmpb, xmask, g1 + (size_t)i * Hc, be1 + (size_t)i * Hc, x1, ybf, 1, 0);

    // h = bf16(relu(W1*x1b + bf1) * mask) -> hbf
    mfma_gemm<1><<<dim3(Tt / 128, HFq / 128, Bq), 256, 0, stream>>>(
        (const __bf16*)ybf, (const __bf16*)(w1b + (size_t)i * HFq * Hc),
        bf1 + (size_t)i * HFq, xmask, hbf, Hc, HFq);

    // f = bf16(W2*h + bf2) -> tmpb
    mfma_gemm<0><<<dim3(Tt / 128, Hc / 128, Bq), 256, 0, stream>>>(
        (const __bf16*)hbf, (const __bf16*)(w2b + (size_t)i * Hc * HFq),
        bf2 + (size_t)i * Hc, xmask, tmpb, HFq, Hc);

    // x = LN(x1 + f*mask) -> xT
    ln_t<<<(Bq * Tt) / 4, 256, 0, stream>>>(
        x1, tmpb, xmask, g2 + (size_t)i * Hc, be2 + (size_t)i * Hc, xT, nullptr, 0, 1);
  }

  transpose_bwd<<<dim3(Tt / 32, Hc / 32, Bq), dim3(32, 8), 0, stream>>>(xT, xmask, (float*)d_out);
}

// Round 10
// 1839.707 us; speedup vs baseline: 1.1633x; 1.0020x over previous
//
#include <hip/hip_runtime.h>
#include <math.h>

#define Bq 16
#define Hc 384
#define Tt 2048
#define N2 32
#define LYR 6
#define HFq 1536
#define TWOH 768
#define CHUNK 64
#define NCH (Tt/CHUNK)   // 32
#define NJ (Bq*NCH)      // 512 chunk-columns per head
#define UH (NJ*CHUNK)    // 32768 elements per head in U/St/Y layouts

typedef __bf16 bf16x8 __attribute__((ext_vector_type(8)));
typedef float floatx4 __attribute__((ext_vector_type(4)));
typedef _Float16 f16_t;
typedef f16_t fp16x8 __attribute__((ext_vector_type(8)));
typedef f16_t fp16x4 __attribute__((ext_vector_type(4)));

__device__ __forceinline__ unsigned short bfbits(float f) {
  union { float f; unsigned u; } x; x.f = f;
  return (unsigned short)((x.u + 0x7FFF + ((x.u >> 16) & 1)) >> 16);
}
__device__ __forceinline__ float bf2f(unsigned short u) {
  union { unsigned u; float f; } x; x.u = ((unsigned)u) << 16; return x.f;
}

// async global->LDS, 16B per lane; dest is wave-uniform base, HW writes lane i
// at base + i*16B (linear). Source address is per-lane.
__device__ __forceinline__ void gl_lds16(const void* g, void* l) {
  __builtin_amdgcn_global_load_lds(
      (const __attribute__((address_space(1))) void*)g,
      (__attribute__((address_space(3))) void*)l, 16, 0, 0);
}

// ---------------- param precompute (fp64 for accuracy) ----------------
__global__ void param_kernel(const float* __restrict__ log_dt,
                             const float* __restrict__ A_re, const float* __restrict__ A_im,
                             const float* __restrict__ C_re, const float* __restrict__ C_im,
                             float* __restrict__ wre, float* __restrict__ wim,
                             float* __restrict__ cdre, float* __restrict__ cdim,
                             float* __restrict__ wSre, float* __restrict__ wSim) {
  int idx = blockIdx.x * blockDim.x + threadIdx.x;
  if (idx >= LYR * Hc * N2) return;
  int hn = idx / N2;
  double dt = exp((double)log_dt[hn]);
  double are = (double)A_re[idx], aim = (double)A_im[idx];
  double dre = are * dt, dimv = aim * dt;
  double er = exp(dre);
  double wr = er * cos(dimv), wi_ = er * sin(dimv);
  double den = are * are + aim * aim;
  double nr = wr - 1.0, ni = wi_;
  double qr = (nr * are + ni * aim) / den;
  double qi = (ni * are - nr * aim) / den;
  double cr = (double)C_re[idx], ci = (double)C_im[idx];
  cdre[idx] = (float)(2.0 * (cr * qr - ci * qi));
  cdim[idx] = (float)(2.0 * (cr * qi + ci * qr));
  wre[idx] = (float)wr; wim[idx] = (float)wi_;
  double es = exp(dre * (double)CHUNK);
  wSre[idx] = (float)(es * cos(dimv * (double)CHUNK));
  wSim[idx] = (float)(es * sin(dimv * (double)CHUNK));
}

// ---------------- weight fp32 -> bf16 (RNE) ----------------
__global__ void cvt_bf16_kernel(const float* __restrict__ in, unsigned short* __restrict__ out,
                                int n4) {
  int idx = blockIdx.x * 256 + threadIdx.x;
  if (idx >= n4) return;
  float4 v = ((const float4*)in)[idx];
  ushort4 o;
  o.x = bfbits(v.x); o.y = bfbits(v.y); o.z = bfbits(v.z); o.w = bfbits(v.w);
  ((ushort4*)out)[idx] = o;
}

// ---------------- transpose (B,C,T) -> (B,T,C) ----------------
__global__ __launch_bounds__(256) void transpose_fwd(const float* __restrict__ in,
                                                     float* __restrict__ out) {
  __shared__ float tile[32][33];
  int tx = threadIdx.x, ty = threadIdx.y;
  int t0 = blockIdx.x * 32, c0 = blockIdx.y * 32, b = blockIdx.z;
#pragma unroll
  for (int k = 0; k < 4; k++)
    tile[ty + 8 * k][tx] = in[((size_t)(b * Hc + c0 + ty + 8 * k)) * Tt + t0 + tx];
  __syncthreads();
#pragma unroll
  for (int k = 0; k < 4; k++)
    out[((size_t)(b * Tt + t0 + ty + 8 * k)) * Hc + c0 + tx] = tile[tx][ty + 8 * k];
}

// ---------------- transpose (B,T,C) -> (B,C,T) with mask ----------------
__global__ __launch_bounds__(256) void transpose_bwd(const float* __restrict__ in,
                                                     const float* __restrict__ mask,
                                                     float* __restrict__ out) {
  __shared__ float tile[32][33];
  int tx = threadIdx.x, ty = threadIdx.y;
  int t0 = blockIdx.x * 32, c0 = blockIdx.y * 32, b = blockIdx.z;
#pragma unroll
  for (int k = 0; k < 4; k++)
    tile[ty + 8 * k][tx] = in[((size_t)(b * Tt + t0 + ty + 8 * k)) * Hc + c0 + tx];
  __syncthreads();
  float mv = mask[(size_t)b * Tt + t0 + tx];
#pragma unroll
  for (int k = 0; k < 4; k++)
    out[((size_t)(b * Hc + c0 + ty + 8 * k)) * Tt + t0 + tx] = tile[tx][ty + 8 * k] * mv;
}

// ---------------- pack: xT (B,T,C) fp32 * mask -> U[h][j][tau] fp16 ----------------
__global__ __launch_bounds__(256) void pack_u(const float* __restrict__ xT,
                                              const float* __restrict__ mask,
                                              f16_t* __restrict__ U) {
  __shared__ float tile[64][65];
  int tid = threadIdx.x;
  int t0 = blockIdx.x * 64, h0 = blockIdx.y * 64, b = blockIdx.z;
#pragma unroll
  for (int p = 0; p < 4; p++) {
    int idx = p * 256 + tid;
    int row = idx >> 4, c4 = (idx & 15) * 4;
    float4 v = *(const float4*)&xT[((size_t)(b * Tt + t0 + row)) * Hc + h0 + c4];
    float mv = mask[(size_t)b * Tt + t0 + row];
    tile[row][c4] = v.x * mv; tile[row][c4 + 1] = v.y * mv;
    tile[row][c4 + 2] = v.z * mv; tile[row][c4 + 3] = v.w * mv;
  }
  __syncthreads();
#pragma unroll
  for (int p = 0; p < 2; p++) {
    int idx = p * 256 + tid;
    int hr = idx >> 3, g = (idx & 7) * 8;
    fp16x8 o;
#pragma unroll
    for (int i = 0; i < 8; i++) o[i] = (f16_t)tile[g + i][hr];
    *(fp16x8*)&U[(size_t)(h0 + hr) * UH + (size_t)b * Tt + t0 + g] = o;
  }
}

// ---------------- build per-head matrices: Ag = [T | V] (64x128), Wg (64x64) ----------------
__global__ __launch_bounds__(256) void build_mats(
    const float* __restrict__ wre, const float* __restrict__ wim,
    const float* __restrict__ cdre, const float* __restrict__ cdim,
    f16_t* __restrict__ Ag, f16_t* __restrict__ Wg) {
  __shared__ float pre[65][32], pim[65][32], Kc[64], cdr_s[32], cdi_s[32];
  int h = blockIdx.x, tid = threadIdx.x;
  if (tid < 32) {
    float wr = wre[h * N2 + tid], wi = wim[h * N2 + tid];
    cdr_s[tid] = cdre[h * N2 + tid];
    cdi_s[tid] = cdim[h * N2 + tid];
    float pr = 1.f, pi = 0.f;
    for (int p = 0; p <= 64; p++) {
      pre[p][tid] = pr; pim[p][tid] = pi;
      float nr2 = pr * wr - pi * wi;
      pi = pr * wi + pi * wr;
      pr = nr2;
    }
  }
  __syncthreads();
  if (tid < 64) {
    float s = 0.f;
    for (int n = 0; n < 32; n++)
      s = fmaf(cdr_s[n], pre[tid][n], fmaf(-cdi_s[n], pim[tid][n], s));
    Kc[tid] = s;
  }
  __syncthreads();
  for (int i = tid; i < 64 * 128; i += 256) {
    int m = i >> 7, k = i & 127;
    float v;
    if (k < 64) {
      v = (m >= k) ? Kc[m - k] : 0.f;
    } else {
      int kk = k - 64, n = kk >> 1;
      v = (kk & 1) ? -fmaf(cdr_s[n], pim[m + 1][n], cdi_s[n] * pre[m + 1][n])
                   :  fmaf(cdr_s[n], pre[m + 1][n], -cdi_s[n] * pim[m + 1][n]);
    }
    Ag[(size_t)h * 8192 + i] = (f16_t)v;
  }
  for (int i = tid; i < 64 * 64; i += 256) {
    int m = i >> 6, tau = i & 63, n = m >> 1;
    float v = (m & 1) ? pim[63 - tau][n] : pre[63 - tau][n];
    Wg[(size_t)h * 4096 + i] = (f16_t)v;
  }
}

// ---------------- fused state GEMM + chunk prefix (per head) ----------------
// Block = one head h, 512 threads. Computes St_local = Wg.U for all 512 j in
// LDS, runs the (b,n) prefix in-LDS, writes carry-in states once to HBM.
__global__ __launch_bounds__(512) void gemm_state_prefix(
    const f16_t* __restrict__ U, const f16_t* __restrict__ Wg,
    const float* __restrict__ wSre, const float* __restrict__ wSim,
    f16_t* __restrict__ St) {
  __shared__ f16_t Aw[64][72];
  __shared__ f16_t Bu[128][72];
  __shared__ f16_t Sl[512][66];   // [j][m], 66-pad -> bank stride 33 (coprime 32)
  int h = blockIdx.x, tid = threadIdx.x;
  {
    int row = tid >> 3, c8 = (tid & 7) * 8;
    *(fp16x8*)&Aw[row][c8] = *(const fp16x8*)&Wg[(size_t)h * 4096 + row * 64 + c8];
  }
  int wave = tid >> 6, lane = tid & 63, l16 = lane & 15, quad = lane >> 4;
  int m0 = (wave & 3) * 16;
  int jh = wave >> 2;             // j-half within the 128-j chunk
  for (int jc = 0; jc < 4; jc++) {
    __syncthreads();              // Bu (and Aw on jc=0) safe to (over)write/visible
#pragma unroll
    for (int p = 0; p < 2; p++) {
      int idx = p * 512 + tid;
      int row = idx >> 3, c8 = (idx & 7) * 8;
      *(fp16x8*)&Bu[row][c8] =
          *(const fp16x8*)&U[(size_t)h * UH + (size_t)(jc * 128 + row) * CHUNK + c8];
    }
    __syncthreads();
    floatx4 acc[4];
#pragma unroll
    for (int jt = 0; jt < 4; jt++) acc[jt] = (floatx4){0.f, 0.f, 0.f, 0.f};
#pragma unroll
    for (int kk = 0; kk < 2; kk++) {
      fp16x8 a = *(const fp16x8*)&Aw[m0 + l16][kk * 32 + quad * 8];
#pragma unroll
      for (int jt = 0; jt < 4; jt++) {
        fp16x8 bb = *(const fp16x8*)&Bu[jh * 64 + jt * 16 + l16][kk * 32 + quad * 8];
        acc[jt] = __builtin_amdgcn_mfma_f32_16x16x32_f16(a, bb, acc[jt], 0, 0, 0);
      }
    }
#pragma unroll
    for (int jt = 0; jt < 4; jt++) {
      int j = jc * 128 + jh * 64 + jt * 16 + l16;
      union { unsigned u[2]; f16_t hh[4]; } pk;
#pragma unroll
      for (int r = 0; r < 4; r++) pk.hh[r] = (f16_t)acc[jt][r];
      *(unsigned*)&Sl[j][m0 + quad * 4] = pk.u[0];
      *(unsigned*)&Sl[j][m0 + quad * 4 + 2] = pk.u[1];
    }
  }
  __syncthreads();
  // prefix: thread = b*32 + n; carry over 32 chunks of batch b, mode n (fp32)
  {
    int b = tid >> 5, n = tid & 31;
    float wr = wSre[h * N2 + n], wi = wSim[h * N2 + n];
    float cr = 0.f, ci = 0.f;
    for (int c = 0; c < NCH; c++) {
      int j = b * NCH + c;
      union { unsigned u; f16_t hh[2]; } in, out;
      in.u = *(unsigned*)&Sl[j][2 * n];
      out.hh[0] = (f16_t)cr; out.hh[1] = (f16_t)ci;
      *(unsigned*)&Sl[j][2 * n] = out.u;
      float c0 = cr;
      cr = fmaf(wr, c0, fmaf(-wi, ci, (float)in.hh[0]));
      ci = fmaf(wr, ci, fmaf(wi, c0, (float)in.hh[1]));
    }
  }
  __syncthreads();
  // writeout: thread j writes its 64 carry-in values (128B) coalesced
  {
    int j = tid;
#pragma unroll
    for (int i = 0; i < 8; i++) {
      unsigned b4[4];
#pragma unroll
      for (int q = 0; q < 4; q++) b4[q] = *(unsigned*)&Sl[j][i * 8 + q * 2];
      *(uint4*)&St[(size_t)h * UH + (size_t)j * CHUNK + i * 8] = *(uint4*)b4;
    }
  }
}

// ---------------- out GEMM: Y = gelu([T|V].[U;S0] + D*u), bf16 out [h][j][tau] ----------------
__global__ __launch_bounds__(256) void gemm_out(
    const f16_t* __restrict__ U, const f16_t* __restrict__ Ag,
    const f16_t* __restrict__ St, const float* __restrict__ Dv,
    unsigned short* __restrict__ Yb) {
  __shared__ f16_t Aa[64][136];
  __shared__ f16_t Bb[128][136];
  int tid = threadIdx.x;
  int j0 = blockIdx.x * 128, h = blockIdx.y;
#pragma unroll
  for (int p = 0; p < 4; p++) {
    int idx = p * 256 + tid;
    int row = idx >> 4, c8 = (idx & 15) * 8;
    *(fp16x8*)&Aa[row][c8] = *(const fp16x8*)&Ag[(size_t)h * 8192 + row * 128 + c8];
  }
#pragma unroll
  for (int p = 0; p < 4; p++) {
    int idx = p * 256 + tid;
    int row = idx >> 3, c8 = (idx & 7) * 8;
    *(fp16x8*)&Bb[row][c8] =
        *(const fp16x8*)&U[(size_t)h * UH + (size_t)(j0 + row) * CHUNK + c8];
    *(fp16x8*)&Bb[row][64 + c8] =
        *(const fp16x8*)&St[(size_t)h * UH + (size_t)(j0 + row) * CHUNK + c8];
  }
  __syncthreads();
  int wave = tid >> 6, lane = tid & 63, l16 = lane & 15, quad = lane >> 4;
  int m0 = wave * 16;
  floatx4 acc[8];
#pragma unroll
  for (int jt = 0; jt < 8; jt++) acc[jt] = (floatx4){0.f, 0.f, 0.f, 0.f};
#pragma unroll
  for (int kk = 0; kk < 4; kk++) {
    fp16x8 a = *(const fp16x8*)&Aa[m0 + l16][kk * 32 + quad * 8];
#pragma unroll
    for (int jt = 0; jt < 8; jt++) {
      fp16x8 bb = *(const fp16x8*)&Bb[jt * 16 + l16][kk * 32 + quad * 8];
      acc[jt] = __builtin_amdgcn_mfma_f32_16x16x32_f16(a, bb, acc[jt], 0, 0, 0);
    }
  }
  float d = Dv[h];
  int tb = m0 + quad * 4;
#pragma unroll
  for (int jt = 0; jt < 8; jt++) {
    int jr = jt * 16 + l16;
    fp16x4 u4 = *(const fp16x4*)&Bb[jr][tb];
    ushort4 o;
#pragma unroll
    for (int r = 0; r < 4; r++) {
      float v = fmaf(d, (float)u4[r], acc[jt][r]);
      v = 0.5f * v * (1.0f + erff(v * 0.70710678118654752f));
      ((unsigned short*)&o)[r] = bfbits(v);
    }
    *(ushort4*)&Yb[(size_t)h * UH + (size_t)(j0 + jr) * CHUNK + tb] = o;
  }
}

// ---------------- unpack: Yb[h][j][tau] bf16 -> ybf (B,T,C) bf16 ----------------
__global__ __launch_bounds__(256) void unpack_y(const unsigned short* __restrict__ Yb,
                                                unsigned short* __restrict__ yb) {
  __shared__ unsigned short tile[64][65];
  int tid = threadIdx.x;
  int t0 = blockIdx.x * 64, h0 = blockIdx.y * 64, b = blockIdx.z;
#pragma unroll
  for (int p = 0; p < 2; p++) {
    int idx = p * 256 + tid;
    int hr = idx >> 3, g = (idx & 7) * 8;
    uint4 v = *(const uint4*)&Yb[(size_t)(h0 + hr) * UH + (size_t)b * Tt + t0 + g];
    const unsigned short* s = (const unsigned short*)&v;
#pragma unroll
    for (int i = 0; i < 8; i++) tile[hr][g + i] = s[i];
  }
  __syncthreads();
#pragma unroll
  for (int p = 0; p < 2; p++) {
    int idx = p * 256 + tid;
    int tr = idx >> 3, g = (idx & 7) * 8;
    unsigned short o[8];
#pragma unroll
    for (int i = 0; i < 8; i++) o[i] = tile[g + i][tr];
    *(uint4*)&yb[((size_t)(b * Tt + t0 + tr)) * Hc + h0 + g] = *(uint4*)o;
  }
}

// ---------------- MFMA GEMM: out(B,T,N) = act(B,T,K) x W(N,K)^T, bf16 out ----------------
// T3+T4: 3-buffer LDS ring, counted s_waitcnt vmcnt(N) + raw s_barrier (one per
// k-step), 2 k-tiles in flight. T2: bank-conflict-free via pre-swizzled global
// source (LDS dest stays linear for global_load_lds) + matching XOR on ds_read.
// EPI 1 uses BM=256 (8 waves, 512 threads): LDS 72KB -> 2 blocks/CU (50% occ
// ceiling vs 37.5% at BM=128) and 3 gl_lds/wave/step instead of 4.
// EPI 0: outb = bf16(acc + bias)           (BM=128)
// EPI 1: outb = bf16(relu(acc + bias)*mask)(BM=256)
// EPI 2: GLU, W has 2N rows                (BM=128)
template <int EPI>
__global__ __launch_bounds__((EPI == 1) ? 512 : 256) void mfma_gemm(
    const __bf16* __restrict__ act, const __bf16* __restrict__ W,
    const float* __restrict__ bias, const float* __restrict__ mask,
    unsigned short* __restrict__ outb, int K, int NOUT) {
  constexpr int BM = (EPI == 1) ? 256 : 128;
  __shared__ __bf16 As[3][BM][32];
  __shared__ __bf16 Bs[3][128][32];
  __shared__ __bf16 Bs2[(EPI == 2) ? 3 : 1][(EPI == 2) ? 128 : 1][32];
  int tid = threadIdx.x;
  int b = blockIdx.z;
  int t0 = blockIdx.x * BM, n0 = blockIdx.y * 128;
  int wave = tid >> 6, lane = tid & 63, l16 = lane & 15, quad = lane >> 4;
  int wm = wave >> 1, wn = wave & 1;   // wm in [0, BM/64)

  floatx4 acc[4][4];
  floatx4 accg[(EPI == 2) ? 4 : 1][4];
#pragma unroll
  for (int i = 0; i < 4; i++)
#pragma unroll
    for (int j = 0; j < 4; j++) {
      acc[i][j] = (floatx4){0.f, 0.f, 0.f, 0.f};
      if constexpr (EPI == 2) accg[i][j] = (floatx4){0.f, 0.f, 0.f, 0.f};
    }

  // staging: wave w covers rows [w*16,+16) (+ row-stride per round); lane l
  // sources row +(l>>2), source chunk pre-swizzled c' = (l&3)^((l>>3)&3) so
  // LDS slot c of row r holds source chunk c ^ ((r>>1)&3).
  int srow = wave * 16 + (lane >> 2);
  int scol = (((lane & 3) ^ ((lane >> 3) & 3)) * 8);
  const __bf16* aSrc = act + ((size_t)(b * Tt + t0 + srow)) * K + scol;
  const __bf16* bSrc = W + (size_t)(n0 + srow) * K + scol;
  const __bf16* gSrc = W + (size_t)(NOUT + n0 + srow) * K + scol;  // EPI2 only

  auto stage = [&](int buf, int k0) {
    if constexpr (BM == 256) {
      gl_lds16(aSrc + k0, &As[buf][wave * 16][0]);
      gl_lds16(aSrc + k0 + (size_t)128 * K, &As[buf][wave * 16 + 128][0]);
      gl_lds16(bSrc + k0, &Bs[buf][wave * 16][0]);
    } else {
      gl_lds16(aSrc + k0, &As[buf][wave * 16][0]);
      gl_lds16(aSrc + k0 + (size_t)64 * K, &As[buf][wave * 16 + 64][0]);
      gl_lds16(bSrc + k0, &Bs[buf][wave * 16][0]);
      gl_lds16(bSrc + k0 + (size_t)64 * K, &Bs[buf][wave * 16 + 64][0]);
      if constexpr (EPI == 2) {
        gl_lds16(gSrc + k0, &Bs2[buf][wave * 16][0]);
        gl_lds16(gSrc + k0 + (size_t)64 * K, &Bs2[buf][wave * 16 + 64][0]);
      }
    }
  };
  constexpr int VC = (EPI == 1) ? 3 : ((EPI == 2) ? 6 : 4);  // loads/wave/tile

  const int NT = K >> 5;           // k-tiles of 32
  int swz = (quad ^ ((l16 >> 1) & 3)) << 4;   // byte offset of swizzled 16B chunk
  stage(0, 0);
  stage(1, 32);                    // NT >= 12 always here
  for (int t = 0; t < NT; ++t) {
    // wait for tile t's own loads (oldest); keep tile t+1's in flight.
    if (t + 1 < NT) {
      asm volatile("s_waitcnt vmcnt(%0)" :: "i"(VC) : "memory");
    } else {
      asm volatile("s_waitcnt vmcnt(0)" ::: "memory");
    }
    __builtin_amdgcn_s_barrier();
    __builtin_amdgcn_sched_barrier(0);
    int cur = t % 3;
    bf16x8 af[4], bfr[4], gfr[(EPI == 2) ? 4 : 1];
#pragma unroll
    for (int i = 0; i < 4; i++)
      af[i] = *(const bf16x8*)((const char*)&As[cur][0][0] +
                               (wm * 64 + i * 16 + l16) * 64 + swz);
#pragma unroll
    for (int j = 0; j < 4; j++) {
      bfr[j] = *(const bf16x8*)((const char*)&Bs[cur][0][0] +
                                (wn * 64 + j * 16 + l16) * 64 + swz);
      if constexpr (EPI == 2)
        gfr[j] = *(const bf16x8*)((const char*)&Bs2[cur][0][0] +
                                  (wn * 64 + j * 16 + l16) * 64 + swz);
    }
    if (t + 2 < NT) stage((t + 2) % 3, (t + 2) * 32);
#pragma unroll
    for (int i = 0; i < 4; i++)
#pragma unroll
      for (int j = 0; j < 4; j++) {
        acc[i][j] = __builtin_amdgcn_mfma_f32_16x16x32_bf16(af[i], bfr[j], acc[i][j], 0, 0, 0);
        if constexpr (EPI == 2)
          accg[i][j] = __builtin_amdgcn_mfma_f32_16x16x32_bf16(af[i], gfr[j], accg[i][j], 0, 0, 0);
      }
  }

  // epilogue: D row = t (i*16 + quad*4 + r), col = n (j*16 + l16)
#pragma unroll
  for (int i = 0; i < 4; i++) {
    int tb = t0 + wm * 64 + i * 16 + quad * 4;
    float mv[4];
    if constexpr (EPI == 1) {
#pragma unroll
      for (int r = 0; r < 4; r++) mv[r] = mask[(size_t)b * Tt + tb + r];
    }
#pragma unroll
    for (int j = 0; j < 4; j++) {
      int n = n0 + wn * 64 + j * 16 + l16;
      float bn = bias[n];
      float bg = (EPI == 2) ? bias[NOUT + n] : 0.f;
#pragma unroll
      for (int r = 0; r < 4; r++) {
        size_t o = ((size_t)(b * Tt + tb + r)) * NOUT + n;
        if constexpr (EPI == 0) {
          outb[o] = bfbits(acc[i][j][r] + bn);
        } else if constexpr (EPI == 1) {
          float v = fmaxf(acc[i][j][r] + bn, 0.f) * mv[r];
          outb[o] = bfbits(v);
        } else {
          float a = acc[i][j][r] + bn;
          float g = accg[i][j][r] + bg;
          outb[o] = bfbits(a / (1.f + expf(-g)));
        }
      }
    }
  }
}

// ---------------- LayerNorm over C: out = LN(in1*f1 + bf16(in2)*f2) ----------------
__global__ __launch_bounds__(256) void ln_t(
    const float* __restrict__ in1, const unsigned short* __restrict__ in2b,
    const float* __restrict__ mask, const float* __restrict__ gamma,
    const float* __restrict__ beta, float* __restrict__ out,
    unsigned short* __restrict__ outb, int m1, int m2) {
  int row = blockIdx.x * 4 + (threadIdx.x >> 6);  // b*Tt + t
  int lane = threadIdx.x & 63;
  float mv = mask[row];
  float f1 = m1 ? mv : 1.f;
  float f2 = m2 ? mv : 1.f;
  size_t base = (size_t)row * Hc;
  float v[6], sum = 0.f, sq = 0.f;
#pragma unroll
  for (int j = 0; j < 6; j++) {
    int idx = lane + 64 * j;
    float a = in1[base + idx] * f1 + bf2f(in2b[base + idx]) * f2;
    v[j] = a; sum += a; sq = fmaf(a, a, sq);
  }
#pragma unroll
  for (int off = 32; off >= 1; off >>= 1) {
    sum += __shfl_xor(sum, off, 64);
    sq  += __shfl_xor(sq,  off, 64);
  }
  float m = sum * (1.f / Hc);
  float var = sq * (1.f / Hc) - m * m;
  float rs = rsqrtf(var + 1e-4f);
#pragma unroll
  for (int j = 0; j < 6; j++) {
    int idx = lane + 64 * j;
    float o = (v[j] - m) * rs * gamma[idx] + beta[idx];
    out[base + idx] = o;
    if (outb) outb[base + idx] = bfbits(o * mv);
  }
}

// ---------------- diagnostic ----------------
__global__ void diag_kernel(float* out, float v) {
  if (blockIdx.x == 0 && threadIdx.x == 0) out[0] = v;
}

extern "C" void kernel_launch(void* const* d_in, const int* in_sizes, int n_in,
                              void* d_out, int out_size, void* d_ws, size_t ws_size,
                              hipStream_t stream) {
  const float* x_in  = (const float*)d_in[0];
  const float* xmask = (const float*)d_in[1];
  const float* log_dt = (const float*)d_in[2];
  const float* A_re = (const float*)d_in[3];
  const float* A_im = (const float*)d_in[4];
  const float* C_re = (const float*)d_in[5];
  const float* C_im = (const float*)d_in[6];
  const float* Dv   = (const float*)d_in[7];
  const float* Wout = (const float*)d_in[8];
  const float* bout = (const float*)d_in[9];
  const float* g1   = (const float*)d_in[10];
  const float* be1  = (const float*)d_in[11];
  const float* W1   = (const float*)d_in[12];
  const float* bf1  = (const float*)d_in[13];
  const float* W2   = (const float*)d_in[14];
  const float* bf2  = (const float*)d_in[15];
  const float* g2   = (const float*)d_in[16];
  const float* be2  = (const float*)d_in[17];

  const size_t NXf   = (size_t)Bq * Hc * Tt;          // 12,582,912 floats
  const size_t NP    = (size_t)LYR * Hc * N2;         // 73,728
  const size_t YBFf  = NXf / 2;                       // bf16 y / x1b region, in floats
  const size_t HBFf  = (size_t)Bq * Tt * HFq / 2;     // bf16 h region, in floats
  const size_t WOUTf = (size_t)LYR * TWOH * Hc / 2;
  const size_t W1f   = (size_t)LYR * HFq * Hc / 2;
  const size_t W2f   = (size_t)LYR * Hc * HFq / 2;

  size_t need = 2 * NXf + YBFf + HBFf + WOUTf + W1f + W2f + 6 * NP;
  if (ws_size / 4 < need) {
    diag_kernel<<<1, 64, 0, stream>>>((float*)d_out, 1000.0f + (float)(ws_size >> 20));
    return;
  }

  float* ws = (float*)d_ws;
  float* xT   = ws;                       // (B,T,C) fp32 layer state
  float* tmp  = xT + NXf;                 // first half: U fp16 overlay; second half: tmpb bf16
  float* ybfF = tmp + NXf;                // bf16 (B,T,C): y, then x1*mask
  float* hbfF = ybfF + YBFf;              // bf16 (B,T,HF): ffn hidden; scan overlays
  float* wobF = hbfF + HBFf;              // bf16 weights
  float* w1bF = wobF + WOUTf;
  float* w2bF = w1bF + W1f;
  float* wre  = w2bF + W2f;
  float* wim  = wre + NP;
  float* cdre = wim + NP;
  float* cdim = cdre + NP;
  float* wSre = cdim + NP;
  float* wSim = wSre + NP;

  unsigned short* ybf = (unsigned short*)ybfF;
  unsigned short* hbf = (unsigned short*)hbfF;
  unsigned short* wob = (unsigned short*)wobF;
  unsigned short* w1b = (unsigned short*)w1bF;
  unsigned short* w2b = (unsigned short*)w2bF;
  float* x1 = (float*)d_out;              // (B,T,C) fp32 post-LN1 lives in d_out

  // scan overlays: U in tmp first half; tmpb bf16 in second half (disjoint);
  // St/Yb/mats in hbf region (dead until FFN)
  f16_t* Ub   = (f16_t*)tmp;                                  // 12.58M fp16 = 6.29M fl
  unsigned short* tmpb = (unsigned short*)(tmp + NXf / 2);    // 12.58M bf16
  f16_t* St16 = (f16_t*)hbfF;                                 // 12.58M fp16
  unsigned short* Ybi = (unsigned short*)(hbfF + YBFf);       // 12.58M bf16
  f16_t* Ag   = (f16_t*)(hbfF + 2 * YBFf);                    // 384*8192 fp16
  f16_t* Wg   = Ag + (size_t)384 * 8192;                      // 384*4096 fp16

  param_kernel<<<(LYR * Hc * N2 + 255) / 256, 256, 0, stream>>>(
      log_dt, A_re, A_im, C_re, C_im, wre, wim, cdre, cdim, wSre, wSim);
  cvt_bf16_kernel<<<(int)(2 * WOUTf + 1023) / 1024, 256, 0, stream>>>(Wout, wob, (int)(WOUTf / 2));
  cvt_bf16_kernel<<<(int)(2 * W1f + 1023) / 1024, 256, 0, stream>>>(W1, w1b, (int)(W1f / 2));
  cvt_bf16_kernel<<<(int)(2 * W2f + 1023) / 1024, 256, 0, stream>>>(W2, w2b, (int)(W2f / 2));
  transpose_fwd<<<dim3(Tt / 32, Hc / 32, Bq), dim3(32, 8), 0, stream>>>(x_in, xT);

  for (int i = 0; i < LYR; i++) {
    size_t po = (size_t)i * Hc * N2;

    // --- S4D scan via MFMA (chunked Toeplitz + carry) ---
    pack_u<<<dim3(Tt / 64, Hc / 64, Bq), 256, 0, stream>>>(xT, xmask, Ub);
    build_mats<<<Hc, 256, 0, stream>>>(wre + po, wim + po, cdre + po, cdim + po, Ag, Wg);
    gemm_state_prefix<<<Hc, 512, 0, stream>>>(Ub, Wg, wSre + po, wSim + po, St16);
    gemm_out<<<dim3(NJ / 128, Hc), 256, 0, stream>>>(Ub, Ag, St16, Dv + (size_t)i * Hc, Ybi);
    unpack_y<<<dim3(Tt / 64, Hc / 64, Bq), 256, 0, stream>>>(Ybi, ybf);

    // glu = bf16(GLU(Wout*y + bout)) -> tmpb
    mfma_gemm<2><<<dim3(Tt / 128, Hc / 128, Bq), 256, 0, stream>>>(
        (const __bf16*)ybf, (const __bf16*)(wob + (size_t)i * TWOH * Hc),
        bout + (size_t)i * TWOH, xmask, tmpb, Hc, Hc);

    // x1 = LN(x*mask + glu) -> d_out fp32 ; x1b = bf16(x1*mask) -> ybf
    ln_t<<<(Bq * Tt) / 4, 256, 0, stream>>>(
        xT, tmpb, xmask, g1 + (size_t)i * Hc, be1 + (size_t)i * Hc, x1, ybf, 1, 0);

    // h = bf16(relu(W1*x1b + bf1) * mask) -> hbf   (BM=256, 8 waves)
    mfma_gemm<1><<<dim3(Tt / 256, HFq / 128, Bq), 512, 0, stream>>>(
        (const __bf16*)ybf, (const __bf16*)(w1b + (size_t)i * HFq * Hc),
        bf1 + (size_t)i * HFq, xmask, hbf, Hc, HFq);

    // f = bf16(W2*h + bf2) -> tmpb
    mfma_gemm<0><<<dim3(Tt / 128, Hc / 128, Bq), 256, 0, stream>>>(
        (const __bf16*)hbf, (const __bf16*)(w2b + (size_t)i * Hc * HFq),
        bf2 + (size_t)i * Hc, xmask, tmpb, HFq, Hc);

    // x = LN(x1 + f*mask) -> xT
    ln_t<<<(Bq * Tt) / 4, 256, 0, stream>>>(
        x1, tmpb, xmask, g2 + (size_t)i * Hc, be2 + (size_t)i * Hc, xT, nullptr, 0, 1);
  }

  transpose_bwd<<<dim3(Tt / 32, Hc / 32, Bq), dim3(32, 8), 0, stream>>>(xT, xmask, (float*)d_out);
}